// Round 3
// baseline (1555.715 us; speedup 1.0000x reference)
//
#include <hip/hip_runtime.h>

// ---------------------------------------------------------------------------
// out[b,t,f] = sum_d x[b,t,d] * (W[d,f] / scale[f])
// GEMM: M=8192 (B*T), K=4096 (D), N=16384 (F)
// Pipeline: x->bf16 (ws), W int -> bf16 W^T (ws), then 256x256-tile 8-phase
// deep-pipelined bf16 MFMA GEMM (T2 LDS swizzle + counted vmcnt(8) with both
// operands staged 2 tiles ahead + T5 setprio), 1/scale epilogue.
// ws: [0,64MiB) Xbf, [64MiB,192MiB) WTbf.
// ---------------------------------------------------------------------------

namespace {

constexpr int MD = 8192;    // B*T
constexpr int ND = 16384;   // F
constexpr int KD = 4096;    // D
constexpr int NT = KD / 64; // 64 k-tiles of BK=64

typedef __bf16 bf16x8 __attribute__((ext_vector_type(8)));
typedef float  f32x4  __attribute__((ext_vector_type(4)));
typedef float  fl4    __attribute__((ext_vector_type(4)));
typedef unsigned int u32x4 __attribute__((ext_vector_type(4)));

__device__ __forceinline__ unsigned int f2bf(float f) {
  unsigned int u = __float_as_uint(f);
  return (u + 0x7FFFu + ((u >> 16) & 1u)) >> 16;
}

// ---- x fp32 [M][K] -> bf16 [M][K] ----------------------------------------
__global__ __launch_bounds__(256) void convert_x_kernel(
    const float* __restrict__ x, unsigned short* __restrict__ xb) {
  size_t i = ((size_t)blockIdx.x * 256 + threadIdx.x) * 8;
  fl4 a = *(const fl4*)(x + i);
  fl4 b = *(const fl4*)(x + i + 4);
  u32x4 o;
  o.x = f2bf(a.x) | (f2bf(a.y) << 16);
  o.y = f2bf(a.z) | (f2bf(a.w) << 16);
  o.z = f2bf(b.x) | (f2bf(b.y) << 16);
  o.w = f2bf(b.z) | (f2bf(b.w) << 16);
  *(u32x4*)(xb + i) = o;
}

// ---- W int32 [K][N] -> bf16 W^T [N][K] ------------------------------------
__global__ __launch_bounds__(256) void transpose_w_kernel(
    const int* __restrict__ W, unsigned short* __restrict__ WT) {
  constexpr int KC = 64;
  const int nb = blockIdx.x & 63;
  const int kb = blockIdx.x >> 6;
  const int n  = nb * 256 + threadIdx.x;
  const int k0 = kb * KC;

  unsigned int buf[KC / 2];
  const int* src = W + (size_t)k0 * ND + n;
#pragma unroll
  for (int i = 0; i < KC; i += 2) {
    int v0 = src[(size_t)i * ND];
    int v1 = src[(size_t)(i + 1) * ND];
    buf[i >> 1] = f2bf((float)v0) | (f2bf((float)v1) << 16);
  }
  u32x4* dst = (u32x4*)(WT + (size_t)n * KD + k0);
#pragma unroll
  for (int j = 0; j < KC / 8; ++j) {
    u32x4 o;
    o.x = buf[4 * j + 0];
    o.y = buf[4 * j + 1];
    o.z = buf[4 * j + 2];
    o.w = buf[4 * j + 3];
    dst[j] = o;
  }
}

// ---- 256x256 8-phase GEMM -------------------------------------------------

#define GLL16(g, l)                                                  \
  __builtin_amdgcn_global_load_lds(                                  \
      (const __attribute__((address_space(1))) void*)(g),            \
      (__attribute__((address_space(3))) void*)(l), 16, 0, 0)

#define BAR()        asm volatile("s_barrier" ::: "memory")
#define WAIT_LGKM0() asm volatile("s_waitcnt lgkmcnt(0)" ::: "memory")
#define WAIT_VM8()   asm volatile("s_waitcnt vmcnt(8)" ::: "memory")
#define PRIO1()      __builtin_amdgcn_s_setprio(1)
#define PRIO0()      __builtin_amdgcn_s_setprio(0)

// one "half-tile" = 128 rows x 64 bf16 (16 KB) = 2 global_load_lds per wave.
// LDS dest is linear; source col is pre-swizzled (rule #21) so that
// LDS[row][col'] = G[row][col' ^ ((row&7)<<4 bytes)].
__device__ __forceinline__ void stage_half(const unsigned short* g0,
                                           unsigned short* lbase, int w) {
  char* l = (char*)lbase + w * 1024;
  GLL16(g0, l);
  GLL16(g0 + (size_t)64 * KD, l + 8192);
}

// ds_read of one MFMA A/B fragment with the read-side swizzle
#define RD_A(DST, MOFF)                                                       \
  _Pragma("unroll") for (int mi = 0; mi < 4; ++mi)                            \
  _Pragma("unroll") for (int kk = 0; kk < 2; ++kk)                            \
      DST[mi][kk] = *(const bf16x8*)(Ard + (size_t)((MOFF + mi) * 16 + r15) * \
                                               128 +                          \
                                     ((kk * 64 + hi16) ^ sw16));

#define RD_B(DST, NOFF)                                                       \
  _Pragma("unroll") for (int ni = 0; ni < 2; ++ni)                            \
  _Pragma("unroll") for (int kk = 0; kk < 2; ++kk)                            \
      DST[ni][kk] = *(const bf16x8*)(Brd + (size_t)((NOFF + ni) * 16 + r15) * \
                                               128 +                          \
                                     ((kk * 64 + hi16) ^ sw16));

#define QUAD(AARR, BARR, MB, NB)                                              \
  _Pragma("unroll") for (int mi = 0; mi < 4; ++mi)                            \
  _Pragma("unroll") for (int ni = 0; ni < 2; ++ni)                            \
  _Pragma("unroll") for (int kk = 0; kk < 2; ++kk)                            \
      acc[MB + mi][NB + ni] = __builtin_amdgcn_mfma_f32_16x16x32_bf16(        \
          AARR[mi][kk], BARR[ni][kk], acc[MB + mi][NB + ni], 0, 0, 0);

__global__ __launch_bounds__(512, 2) void gemm_kernel(
    const unsigned short* __restrict__ A,   // bf16 [M][K]
    const unsigned short* __restrict__ Bt,  // bf16 [N][K]
    const float* __restrict__ scale,        // [N]
    float* __restrict__ C) {                // f32 [M][N]
  // [buf][256 rows][64 bf16]; half0 = rows 0-127, half1 = rows 128-255
  __shared__ __align__(16) unsigned short Asmem[2][16384];
  __shared__ __align__(16) unsigned short Bsmem[2][16384];

  const int tid  = threadIdx.x;
  const int lane = tid & 63;
  const int w    = tid >> 6;   // wave 0..7
  const int wm   = w >> 2;     // 0..1 : owns A rows wm*128..+127
  const int wn   = w & 3;      // 0..3 : owns B cols wn*64..+63

  // grid swizzle: per-XCD chunks are tn-major (each XCD owns 8 exclusive
  // B-panel columns and sweeps all tm) -> B read once chip-wide, A L3-hits.
  const int bid = blockIdx.x;               // 2048 blocks (32 tm x 64 tn)
  const int swz = (bid & 7) * 256 + (bid >> 3);
  const int tm  = swz & 31;
  const int tn  = swz >> 5;
  const size_t brow = (size_t)tm * 256;
  const size_t bcol = (size_t)tn * 256;

  // staging source addressing (pre-swizzled col, see stage_half)
  const int srow = w * 8 + (lane >> 3);                        // 0..63
  const int scol = (((lane & 7) ^ ((lane >> 3) & 7)) << 3);    // elems
  const unsigned short* Ag = A  + (brow + srow) * (size_t)KD + scol;
  const unsigned short* Bg = Bt + (bcol + srow) * (size_t)KD + scol;

  // fragment-read addressing
  const int r15  = lane & 15;
  const int hi16 = (lane >> 4) << 4;   // byte col within row
  const int sw16 = (lane & 7) << 4;    // read-side swizzle XOR

  f32x4 acc[8][4];
  const f32x4 z = {0.f, 0.f, 0.f, 0.f};
#pragma unroll
  for (int i = 0; i < 8; ++i)
#pragma unroll
    for (int j = 0; j < 4; ++j) acc[i][j] = z;

  // ---- prologue: tiles 0 and 1 fully staged; keep tile1's 8 in flight ----
  stage_half(Ag,                          &Asmem[0][0],    w);
  stage_half(Ag + (size_t)128 * KD,       &Asmem[0][8192], w);
  stage_half(Bg,                          &Bsmem[0][0],    w);
  stage_half(Bg + (size_t)128 * KD,       &Bsmem[0][8192], w);
  stage_half(Ag + 64,                     &Asmem[1][0],    w);
  stage_half(Ag + (size_t)128 * KD + 64,  &Asmem[1][8192], w);
  stage_half(Bg + 64,                     &Bsmem[1][0],    w);
  stage_half(Bg + (size_t)128 * KD + 64,  &Bsmem[1][8192], w);
  WAIT_VM8();  // tile0 resident; tile1's 8 loads stay in flight
  BAR();

  bf16x8 aL[4][2], aH[4][2], bL[2][2], bH[2][2];

  // ---- main loop: 32 iters x 2 K-tiles, 4 phases per tile ----
  for (int it = 0; it < NT / 2; ++it) {
    const int T = 2 * it;
#pragma unroll
    for (int h = 0; h < 2; ++h) {
      const char* Ard = (const char*)&Asmem[h][0] + wm * 16384;
      const char* Brd =
          (const char*)&Bsmem[h][0] + (wn >> 1) * 16384 + (wn & 1) * 64 * 128;
      // both operands staged 2 tiles ahead into the same-parity buffer
      const size_t kb2 = (size_t)((T + 2 + h) & (NT - 1)) * 64;
      unsigned short* Adst = &Asmem[h][0];
      unsigned short* Bdst = &Bsmem[h][0];

      // PH1: read aL + bL ; MFMA m0-3 x n0-1
      RD_A(aL, 0);
      RD_B(bL, 0);
      BAR();
      WAIT_LGKM0();
      PRIO1();
      QUAD(aL, bL, 0, 0);
      PRIO0();
      BAR();

      // PH2: read aH + bH ; MFMA m4-7 x n0-1
      // (all LDS reads of buf h are complete at this phase's trailing bar)
      RD_A(aH, 4);
      RD_B(bH, 2);
      BAR();
      WAIT_LGKM0();
      PRIO1();
      QUAD(aH, bL, 4, 0);
      PRIO0();
      BAR();

      // PH3: stage tile(T+2+h) half0 (A+B) ; MFMA m0-3 x n2-3
      stage_half(Ag + kb2, Adst, w);
      stage_half(Bg + kb2, Bdst, w);
      PRIO1();
      QUAD(aL, bH, 0, 2);
      PRIO0();
      BAR();

      // PH4: stage tile(T+2+h) half1 (A+B) ; MFMA m4-7 x n2-3 ;
      // counted vmcnt(8): drains tile(T+1+h)'s 8 loads (4-5 phases old),
      // keeps tile(T+2+h)'s 8 in flight across the barrier.
      stage_half(Ag + (size_t)128 * KD + kb2, Adst + 8192, w);
      stage_half(Bg + (size_t)128 * KD + kb2, Bdst + 8192, w);
      PRIO1();
      QUAD(aH, bH, 4, 2);
      PRIO0();
      WAIT_VM8();
      BAR();
    }
  }

  // ---- epilogue: acc * (1/scale[col]) -> C ----
  const int r4 = (lane >> 4) << 2;
#pragma unroll
  for (int ni = 0; ni < 4; ++ni) {
    const size_t col = bcol + wn * 64 + ni * 16 + r15;
    const float inv = 1.0f / scale[col];
#pragma unroll
    for (int mi = 0; mi < 8; ++mi) {
      float* cp = C + (brow + wm * 128 + mi * 16 + r4) * (size_t)ND + col;
#pragma unroll
      for (int r = 0; r < 4; ++r) cp[(size_t)r * ND] = acc[mi][ni][r] * inv;
    }
  }
}

}  // namespace

extern "C" void kernel_launch(void* const* d_in, const int* in_sizes, int n_in,
                              void* d_out, int out_size, void* d_ws,
                              size_t ws_size, hipStream_t stream) {
  const float* x     = (const float*)d_in[0];
  const int*   W     = (const int*)d_in[1];
  const float* scale = (const float*)d_in[2];
  float*       out   = (float*)d_out;

  unsigned short* xb = (unsigned short*)d_ws;
  unsigned short* wt = (unsigned short*)((char*)d_ws + (size_t)MD * KD * 2);

  convert_x_kernel<<<16384, 256, 0, stream>>>(x, xb);
  transpose_w_kernel<<<4096, 256, 0, stream>>>(W, wt);
  gemm_kernel<<<2048, 512, 0, stream>>>(xb, wt, scale, out);
}

// Round 4
// 1545.398 us; speedup vs baseline: 1.0067x; 1.0067x over previous
//
#include <hip/hip_runtime.h>

// ---------------------------------------------------------------------------
// out[b,t,f] = sum_d x[b,t,d] * (W[d,f] / scale[f])
// GEMM: M=8192 (B*T), K=4096 (D), N=16384 (F)
// Pipeline: x->bf16 (ws), W int -> bf16 W^T (ws), then 256x256-tile bf16 MFMA
// GEMM: T2 LDS swizzle + 2-tile-deep staging with counted vmcnt(8) + compiler
// -scheduled ds_read/MFMA interleave (no hand barriers inside a K-tile).
// ws: [0,64MiB) Xbf, [64MiB,192MiB) WTbf.
// ---------------------------------------------------------------------------

namespace {

constexpr int MD = 8192;    // B*T
constexpr int ND = 16384;   // F
constexpr int KD = 4096;    // D
constexpr int NT = KD / 64; // 64 k-tiles of BK=64

typedef __bf16 bf16x8 __attribute__((ext_vector_type(8)));
typedef float  f32x4  __attribute__((ext_vector_type(4)));
typedef float  fl4    __attribute__((ext_vector_type(4)));
typedef unsigned int u32x4 __attribute__((ext_vector_type(4)));

__device__ __forceinline__ unsigned int f2bf(float f) {
  unsigned int u = __float_as_uint(f);
  return (u + 0x7FFFu + ((u >> 16) & 1u)) >> 16;
}

// ---- x fp32 [M][K] -> bf16 [M][K] ----------------------------------------
__global__ __launch_bounds__(256) void convert_x_kernel(
    const float* __restrict__ x, unsigned short* __restrict__ xb) {
  size_t i = ((size_t)blockIdx.x * 256 + threadIdx.x) * 8;
  fl4 a = *(const fl4*)(x + i);
  fl4 b = *(const fl4*)(x + i + 4);
  u32x4 o;
  o.x = f2bf(a.x) | (f2bf(a.y) << 16);
  o.y = f2bf(a.z) | (f2bf(a.w) << 16);
  o.z = f2bf(b.x) | (f2bf(b.y) << 16);
  o.w = f2bf(b.z) | (f2bf(b.w) << 16);
  *(u32x4*)(xb + i) = o;
}

// ---- W int32 [K][N] -> bf16 W^T [N][K] ------------------------------------
__global__ __launch_bounds__(256) void transpose_w_kernel(
    const int* __restrict__ W, unsigned short* __restrict__ WT) {
  constexpr int KC = 64;
  const int nb = blockIdx.x & 63;
  const int kb = blockIdx.x >> 6;
  const int n  = nb * 256 + threadIdx.x;
  const int k0 = kb * KC;

  unsigned int buf[KC / 2];
  const int* src = W + (size_t)k0 * ND + n;
#pragma unroll
  for (int i = 0; i < KC; i += 2) {
    int v0 = src[(size_t)i * ND];
    int v1 = src[(size_t)(i + 1) * ND];
    buf[i >> 1] = f2bf((float)v0) | (f2bf((float)v1) << 16);
  }
  u32x4* dst = (u32x4*)(WT + (size_t)n * KD + k0);
#pragma unroll
  for (int j = 0; j < KC / 8; ++j) {
    u32x4 o;
    o.x = buf[4 * j + 0];
    o.y = buf[4 * j + 1];
    o.z = buf[4 * j + 2];
    o.w = buf[4 * j + 3];
    dst[j] = o;
  }
}

// ---- 256x256 GEMM ---------------------------------------------------------

#define GLL16(g, l)                                                  \
  __builtin_amdgcn_global_load_lds(                                  \
      (const __attribute__((address_space(1))) void*)(g),            \
      (__attribute__((address_space(3))) void*)(l), 16, 0, 0)

#define BAR()        asm volatile("s_barrier" ::: "memory")
#define WAIT_LGKM0() asm volatile("s_waitcnt lgkmcnt(0)" ::: "memory")
#define WAIT_VM8()   asm volatile("s_waitcnt vmcnt(8)" ::: "memory")
#define PRIO1()      __builtin_amdgcn_s_setprio(1)
#define PRIO0()      __builtin_amdgcn_s_setprio(0)

// one "half-tile" = 128 rows x 64 bf16 (16 KB) = 2 global_load_lds per wave.
// LDS dest is linear; source col is pre-swizzled (rule #21) so that
// LDS[row][col'] = G[row][col' ^ ((row&7)<<4 bytes)].
__device__ __forceinline__ void stage_half(const unsigned short* g0,
                                           unsigned short* lbase, int w) {
  char* l = (char*)lbase + w * 1024;
  GLL16(g0, l);
  GLL16(g0 + (size_t)64 * KD, l + 8192);
}

// ds_read of one MFMA A/B fragment with the read-side swizzle
#define RD_A(DST, MOFF)                                                       \
  _Pragma("unroll") for (int mi = 0; mi < 4; ++mi)                            \
  _Pragma("unroll") for (int kk = 0; kk < 2; ++kk)                            \
      DST[mi][kk] = *(const bf16x8*)(Ard + (size_t)((MOFF + mi) * 16 + r15) * \
                                               128 +                          \
                                     ((kk * 64 + hi16) ^ sw16));

#define RD_B(DST, NOFF)                                                       \
  _Pragma("unroll") for (int ni = 0; ni < 2; ++ni)                            \
  _Pragma("unroll") for (int kk = 0; kk < 2; ++kk)                            \
      DST[ni][kk] = *(const bf16x8*)(Brd + (size_t)((NOFF + ni) * 16 + r15) * \
                                               128 +                          \
                                     ((kk * 64 + hi16) ^ sw16));

#define QUAD(AARR, BARR, MB, NB)                                              \
  _Pragma("unroll") for (int mi = 0; mi < 4; ++mi)                            \
  _Pragma("unroll") for (int ni = 0; ni < 2; ++ni)                            \
  _Pragma("unroll") for (int kk = 0; kk < 2; ++kk)                            \
      acc[MB + mi][NB + ni] = __builtin_amdgcn_mfma_f32_16x16x32_bf16(        \
          AARR[mi][kk], BARR[ni][kk], acc[MB + mi][NB + ni], 0, 0, 0);

__global__ __launch_bounds__(512, 2) void gemm_kernel(
    const unsigned short* __restrict__ A,   // bf16 [M][K]
    const unsigned short* __restrict__ Bt,  // bf16 [N][K]
    const float* __restrict__ scale,        // [N]
    float* __restrict__ C) {                // f32 [M][N]
  // [buf][256 rows][64 bf16]; half0 = rows 0-127, half1 = rows 128-255
  __shared__ __align__(16) unsigned short Asmem[2][16384];
  __shared__ __align__(16) unsigned short Bsmem[2][16384];

  const int tid  = threadIdx.x;
  const int lane = tid & 63;
  const int w    = tid >> 6;   // wave 0..7
  const int wm   = w >> 2;     // 0..1 : owns A rows wm*128..+127
  const int wn   = w & 3;      // 0..3 : owns B cols wn*64..+63

  // grid swizzle: per-XCD chunks are tn-major (each XCD owns 8 exclusive
  // B-panel columns and sweeps all tm) -> B read once chip-wide, A L3-hits.
  const int bid = blockIdx.x;               // 2048 blocks (32 tm x 64 tn)
  const int swz = (bid & 7) * 256 + (bid >> 3);
  const int tm  = swz & 31;
  const int tn  = swz >> 5;
  const size_t brow = (size_t)tm * 256;
  const size_t bcol = (size_t)tn * 256;

  // staging source addressing (pre-swizzled col, see stage_half)
  const int srow = w * 8 + (lane >> 3);                        // 0..63
  const int scol = (((lane & 7) ^ ((lane >> 3) & 7)) << 3);    // elems
  const unsigned short* Ag = A  + (brow + srow) * (size_t)KD + scol;
  const unsigned short* Bg = Bt + (bcol + srow) * (size_t)KD + scol;

  // fragment-read addressing
  const int r15  = lane & 15;
  const int hi16 = (lane >> 4) << 4;   // byte col within row
  const int sw16 = (lane & 7) << 4;    // read-side swizzle XOR

  f32x4 acc[8][4];
  const f32x4 z = {0.f, 0.f, 0.f, 0.f};
#pragma unroll
  for (int i = 0; i < 8; ++i)
#pragma unroll
    for (int j = 0; j < 4; ++j) acc[i][j] = z;

  // ---- prologue: tiles 0 and 1 fully staged; keep tile1's 8 in flight ----
  stage_half(Ag,                          &Asmem[0][0],    w);
  stage_half(Ag + (size_t)128 * KD,       &Asmem[0][8192], w);
  stage_half(Bg,                          &Bsmem[0][0],    w);
  stage_half(Bg + (size_t)128 * KD,       &Bsmem[0][8192], w);
  stage_half(Ag + 64,                     &Asmem[1][0],    w);
  stage_half(Ag + (size_t)128 * KD + 64,  &Asmem[1][8192], w);
  stage_half(Bg + 64,                     &Bsmem[1][0],    w);
  stage_half(Bg + (size_t)128 * KD + 64,  &Bsmem[1][8192], w);
  WAIT_VM8();  // tile0 resident; tile1's 8 loads stay in flight
  BAR();

  bf16x8 aL[4][2], aH[4][2], bL[2][2], bH[2][2];

  // ---- main loop: 32 iters x 2 K-tiles ----
  // Per K-tile: {24 ds_read + 64 MFMA, compiler-interleaved with fine
  // lgkmcnt} ; lgkmcnt(0)+bar certifies buf h fully read ; restage buf h
  // two tiles ahead ; vmcnt(8)+bar certifies buf h^1 (staged last tile).
  for (int it = 0; it < NT / 2; ++it) {
    const int T = 2 * it;
#pragma unroll
    for (int h = 0; h < 2; ++h) {
      const char* Ard = (const char*)&Asmem[h][0] + wm * 16384;
      const char* Brd =
          (const char*)&Bsmem[h][0] + (wn >> 1) * 16384 + (wn & 1) * 64 * 128;
      const size_t kb2 = (size_t)((T + 2 + h) & (NT - 1)) * 64;
      unsigned short* Adst = &Asmem[h][0];
      unsigned short* Bdst = &Bsmem[h][0];

      // reads + MFMAs: no hand waits; compiler inserts fine-grained lgkmcnt
      // so early quads overlap the remaining read drain.
      RD_A(aL, 0);
      RD_B(bL, 0);
      RD_A(aH, 4);
      RD_B(bH, 2);
      PRIO1();
      QUAD(aL, bL, 0, 0);
      QUAD(aH, bL, 4, 0);
      QUAD(aH, bH, 4, 2);
      QUAD(aL, bH, 0, 2);
      PRIO0();

      // certify all ds_reads of buf h executed, then overwrite it 2 ahead
      WAIT_LGKM0();
      BAR();
      stage_half(Ag + kb2, Adst, w);
      stage_half(Bg + kb2, Bdst, w);
      stage_half(Ag + (size_t)128 * KD + kb2, Adst + 8192, w);
      stage_half(Bg + (size_t)128 * KD + kb2, Bdst + 8192, w);
      // drain tile(T+1+h)'s 8 loads (issued last K-tile, ~1 tile old),
      // keep the 8 just issued in flight across the barrier.
      WAIT_VM8();
      BAR();
    }
  }

  // ---- epilogue: acc * (1/scale[col]) -> C ----
  const int r4 = (lane >> 4) << 2;
#pragma unroll
  for (int ni = 0; ni < 4; ++ni) {
    const size_t col = bcol + wn * 64 + ni * 16 + r15;
    const float inv = 1.0f / scale[col];
#pragma unroll
    for (int mi = 0; mi < 8; ++mi) {
      float* cp = C + (brow + wm * 128 + mi * 16 + r4) * (size_t)ND + col;
#pragma unroll
      for (int r = 0; r < 4; ++r) cp[(size_t)r * ND] = acc[mi][ni][r] * inv;
    }
  }
}

}  // namespace

extern "C" void kernel_launch(void* const* d_in, const int* in_sizes, int n_in,
                              void* d_out, int out_size, void* d_ws,
                              size_t ws_size, hipStream_t stream) {
  const float* x     = (const float*)d_in[0];
  const int*   W     = (const int*)d_in[1];
  const float* scale = (const float*)d_in[2];
  float*       out   = (float*)d_out;

  unsigned short* xb = (unsigned short*)d_ws;
  unsigned short* wt = (unsigned short*)((char*)d_ws + (size_t)MD * KD * 2);

  convert_x_kernel<<<16384, 256, 0, stream>>>(x, xb);
  transpose_w_kernel<<<4096, 256, 0, stream>>>(W, wt);
  gemm_kernel<<<2048, 512, 0, stream>>>(xb, wt, scale, out);
}

// Round 5
// 1540.988 us; speedup vs baseline: 1.0096x; 1.0029x over previous
//
#include <hip/hip_runtime.h>

// ---------------------------------------------------------------------------
// out[b,t,f] = sum_d x[b,t,d] * (W[d,f] / scale[f])
// GEMM: M=8192 (B*T), K=4096 (D), N=16384 (F)
// Pipeline: x->bf16 (ws), W int -> bf16 W^T (ws), then 256x256-tile bf16 MFMA
// GEMM. Sync idiom per verified m201 template: raw s_barrier builtin (no
// memory clobber -> no compiler-forced vmcnt(0) drain), bare counted waitcnt
// asm, sched_barrier(0) pinning. 2-tile-deep staging, vmcnt(8), T2 swizzle,
// T5 setprio. ws: [0,64MiB) Xbf, [64MiB,192MiB) WTbf.
// ---------------------------------------------------------------------------

namespace {

constexpr int MD = 8192;    // B*T
constexpr int ND = 16384;   // F
constexpr int KD = 4096;    // D
constexpr int NT = KD / 64; // 64 k-tiles of BK=64

typedef __bf16 bf16x8 __attribute__((ext_vector_type(8)));
typedef float  f32x4  __attribute__((ext_vector_type(4)));
typedef float  fl4    __attribute__((ext_vector_type(4)));
typedef unsigned int u32x4 __attribute__((ext_vector_type(4)));

__device__ __forceinline__ unsigned int f2bf(float f) {
  unsigned int u = __float_as_uint(f);
  return (u + 0x7FFFu + ((u >> 16) & 1u)) >> 16;
}

// ---- x fp32 [M][K] -> bf16 [M][K] ----------------------------------------
__global__ __launch_bounds__(256) void convert_x_kernel(
    const float* __restrict__ x, unsigned short* __restrict__ xb) {
  size_t i = ((size_t)blockIdx.x * 256 + threadIdx.x) * 8;
  fl4 a = *(const fl4*)(x + i);
  fl4 b = *(const fl4*)(x + i + 4);
  u32x4 o;
  o.x = f2bf(a.x) | (f2bf(a.y) << 16);
  o.y = f2bf(a.z) | (f2bf(a.w) << 16);
  o.z = f2bf(b.x) | (f2bf(b.y) << 16);
  o.w = f2bf(b.z) | (f2bf(b.w) << 16);
  *(u32x4*)(xb + i) = o;
}

// ---- W int32 [K][N] -> bf16 W^T [N][K] ------------------------------------
__global__ __launch_bounds__(256) void transpose_w_kernel(
    const int* __restrict__ W, unsigned short* __restrict__ WT) {
  constexpr int KC = 64;
  const int nb = blockIdx.x & 63;
  const int kb = blockIdx.x >> 6;
  const int n  = nb * 256 + threadIdx.x;
  const int k0 = kb * KC;

  unsigned int buf[KC / 2];
  const int* src = W + (size_t)k0 * ND + n;
#pragma unroll
  for (int i = 0; i < KC; i += 2) {
    int v0 = src[(size_t)i * ND];
    int v1 = src[(size_t)(i + 1) * ND];
    buf[i >> 1] = f2bf((float)v0) | (f2bf((float)v1) << 16);
  }
  u32x4* dst = (u32x4*)(WT + (size_t)n * KD + k0);
#pragma unroll
  for (int j = 0; j < KC / 8; ++j) {
    u32x4 o;
    o.x = buf[4 * j + 0];
    o.y = buf[4 * j + 1];
    o.z = buf[4 * j + 2];
    o.w = buf[4 * j + 3];
    dst[j] = o;
  }
}

// ---- 256x256 GEMM ---------------------------------------------------------

#define GLL16(g, l)                                                  \
  __builtin_amdgcn_global_load_lds(                                  \
      (const __attribute__((address_space(1))) void*)(g),            \
      (__attribute__((address_space(3))) void*)(l), 16, 0, 0)

// m201 idiom: raw barrier builtin, bare waitcnt asm, sched_barrier pinning.
#define BARRIER()    __builtin_amdgcn_s_barrier()
#define WAITL(N)     asm volatile("s_waitcnt lgkmcnt(" #N ")")
#define WAITV8()     asm volatile("s_waitcnt vmcnt(8)")
#define SCHED()      __builtin_amdgcn_sched_barrier(0)
#define PRIO1()      __builtin_amdgcn_s_setprio(1)
#define PRIO0()      __builtin_amdgcn_s_setprio(0)

// one "half-tile" = 128 rows x 64 bf16 (16 KB) = 2 global_load_lds per wave.
// LDS dest is linear; source col is pre-swizzled (rule #21) so that
// LDS[row][col'] = G[row][col' ^ ((row&7)<<4 bytes)].
__device__ __forceinline__ void stage_half(const unsigned short* g0,
                                           unsigned short* lbase, int w) {
  char* l = (char*)lbase + w * 1024;
  GLL16(g0, l);
  GLL16(g0 + (size_t)64 * KD, l + 8192);
}

// ds_read of one MFMA A/B fragment with the read-side swizzle
#define RD_A(DST, MOFF)                                                       \
  _Pragma("unroll") for (int mi = 0; mi < 4; ++mi)                            \
  _Pragma("unroll") for (int kk = 0; kk < 2; ++kk)                            \
      DST[mi][kk] = *(const bf16x8*)(Ard + (size_t)((MOFF + mi) * 16 + r15) * \
                                               128 +                          \
                                     ((kk * 64 + hi16) ^ sw16));

#define RD_B(DST, NOFF)                                                       \
  _Pragma("unroll") for (int ni = 0; ni < 2; ++ni)                            \
  _Pragma("unroll") for (int kk = 0; kk < 2; ++kk)                            \
      DST[ni][kk] = *(const bf16x8*)(Brd + (size_t)((NOFF + ni) * 16 + r15) * \
                                               128 +                          \
                                     ((kk * 64 + hi16) ^ sw16));

#define QUAD(AARR, BARR, MB, NB)                                              \
  _Pragma("unroll") for (int mi = 0; mi < 4; ++mi)                            \
  _Pragma("unroll") for (int ni = 0; ni < 2; ++ni)                            \
  _Pragma("unroll") for (int kk = 0; kk < 2; ++kk)                            \
      acc[MB + mi][NB + ni] = __builtin_amdgcn_mfma_f32_16x16x32_bf16(        \
          AARR[mi][kk], BARR[ni][kk], acc[MB + mi][NB + ni], 0, 0, 0);

__global__ __launch_bounds__(512, 2) void gemm_kernel(
    const unsigned short* __restrict__ A,   // bf16 [M][K]
    const unsigned short* __restrict__ Bt,  // bf16 [N][K]
    const float* __restrict__ scale,        // [N]
    float* __restrict__ C) {                // f32 [M][N]
  // [buf][256 rows][64 bf16]; half0 = rows 0-127, half1 = rows 128-255
  __shared__ __align__(16) unsigned short Asmem[2][16384];
  __shared__ __align__(16) unsigned short Bsmem[2][16384];

  const int tid  = threadIdx.x;
  const int lane = tid & 63;
  const int w    = tid >> 6;   // wave 0..7
  const int wm   = w >> 2;     // 0..1 : owns A rows wm*128..+127
  const int wn   = w & 3;      // 0..3 : owns B cols wn*64..+63

  // grid swizzle: per-XCD chunks are tn-major (each XCD owns 8 exclusive
  // B-panel columns and sweeps all tm).
  const int bid = blockIdx.x;               // 2048 blocks (32 tm x 64 tn)
  const int swz = (bid & 7) * 256 + (bid >> 3);
  const int tm  = swz & 31;
  const int tn  = swz >> 5;
  const size_t brow = (size_t)tm * 256;
  const size_t bcol = (size_t)tn * 256;

  // staging source addressing (pre-swizzled col, see stage_half)
  const int srow = w * 8 + (lane >> 3);                        // 0..63
  const int scol = (((lane & 7) ^ ((lane >> 3) & 7)) << 3);    // elems
  const unsigned short* Ag = A  + (brow + srow) * (size_t)KD + scol;
  const unsigned short* Bg = Bt + (bcol + srow) * (size_t)KD + scol;

  // fragment-read addressing
  const int r15  = lane & 15;
  const int hi16 = (lane >> 4) << 4;   // byte col within row
  const int sw16 = (lane & 7) << 4;    // read-side swizzle XOR

  f32x4 acc[8][4];
  const f32x4 z = {0.f, 0.f, 0.f, 0.f};
#pragma unroll
  for (int i = 0; i < 8; ++i)
#pragma unroll
    for (int j = 0; j < 4; ++j) acc[i][j] = z;

  // ---- prologue: tiles 0 and 1 staged; tile1's 8 loads stay in flight ----
  stage_half(Ag,                          &Asmem[0][0],    w);
  stage_half(Ag + (size_t)128 * KD,       &Asmem[0][8192], w);
  stage_half(Bg,                          &Bsmem[0][0],    w);
  stage_half(Bg + (size_t)128 * KD,       &Bsmem[0][8192], w);
  stage_half(Ag + 64,                     &Asmem[1][0],    w);
  stage_half(Ag + (size_t)128 * KD + 64,  &Asmem[1][8192], w);
  stage_half(Bg + 64,                     &Bsmem[1][0],    w);
  stage_half(Bg + (size_t)128 * KD + 64,  &Bsmem[1][8192], w);
  SCHED();
  WAITV8();  // tile0 resident; tile1's 8 loads in flight
  SCHED();
  BARRIER();

  bf16x8 aL[4][2], aH[4][2], bL[2][2], bH[2][2];

  // ---- main loop: 64 K-tiles ----
#pragma unroll 2
  for (int it = 0; it < NT; ++it) {
    const int h = it & 1;
    const char* Ard = (const char*)&Asmem[h][0] + wm * 16384;
    const char* Brd = (const char*)&Bsmem[h][0] + wn * 8192;
    const size_t kb2 = (size_t)((it + 2) & (NT - 1)) * 64;
    unsigned short* Adst = &Asmem[h][0];
    unsigned short* Bdst = &Bsmem[h][0];

    // issue Q0's 12 reads first (in-order DS returns -> lgkm(12) = aL,bL)
    RD_A(aL, 0);
    RD_B(bL, 0);
    SCHED();
    RD_A(aH, 4);
    RD_B(bH, 2);
    SCHED();
    WAITL(12);   // aL,bL resident
    SCHED();
    PRIO1();
    QUAD(aL, bL, 0, 0);   // 16 MFMA cover the drain of the remaining 12 reads
    PRIO0();
    SCHED();
    WAITL(0);    // all my reads of buf h physically complete
    SCHED();
    PRIO1();
    QUAD(aH, bL, 4, 0);
    QUAD(aH, bH, 4, 2);
    QUAD(aL, bH, 0, 2);
    PRIO0();
    SCHED();
    BARRIER();   // cross-wave: buf h fully read by everyone -> safe to restage
    SCHED();
    stage_half(Ag + kb2,                    Adst, w);
    stage_half(Bg + kb2,                    Bdst, w);
    stage_half(Ag + (size_t)128 * KD + kb2, Adst + 8192, w);
    stage_half(Bg + (size_t)128 * KD + kb2, Bdst + 8192, w);
    SCHED();
    WAITV8();    // drain tile(it+1)'s 8 loads; keep tile(it+2)'s in flight
    SCHED();
    BARRIER();   // buf h^1 (tile it+1) certified for next iteration
  }

  // ---- epilogue: acc * (1/scale[col]) -> C ----
  const int r4 = (lane >> 4) << 2;
#pragma unroll
  for (int ni = 0; ni < 4; ++ni) {
    const size_t col = bcol + wn * 64 + ni * 16 + r15;
    const float inv = 1.0f / scale[col];
#pragma unroll
    for (int mi = 0; mi < 8; ++mi) {
      float* cp = C + (brow + wm * 128 + mi * 16 + r4) * (size_t)ND + col;
#pragma unroll
      for (int r = 0; r < 4; ++r) cp[(size_t)r * ND] = acc[mi][ni][r] * inv;
    }
  }
}

}  // namespace

extern "C" void kernel_launch(void* const* d_in, const int* in_sizes, int n_in,
                              void* d_out, int out_size, void* d_ws,
                              size_t ws_size, hipStream_t stream) {
  const float* x     = (const float*)d_in[0];
  const int*   W     = (const int*)d_in[1];
  const float* scale = (const float*)d_in[2];
  float*       out   = (float*)d_out;

  unsigned short* xb = (unsigned short*)d_ws;
  unsigned short* wt = (unsigned short*)((char*)d_ws + (size_t)MD * KD * 2);

  convert_x_kernel<<<16384, 256, 0, stream>>>(x, xb);
  transpose_w_kernel<<<4096, 256, 0, stream>>>(W, wt);
  gemm_kernel<<<2048, 512, 0, stream>>>(xb, wt, scale, out);
}

// Round 6
// 1337.542 us; speedup vs baseline: 1.1631x; 1.1521x over previous
//
#include <hip/hip_runtime.h>

// ---------------------------------------------------------------------------
// out[b,t,f] = sum_d x[b,t,d] * (W[d,f] / scale[f])
// GEMM: M=8192 (B*T), K=4096 (D), N=16384 (F)
// Pipeline: x->bf16 (ws), W int -> bf16 W^T (ws), then 256x256-tile bf16 MFMA
// GEMM. Round-6 change: 2D XCD supertiling (A row-band pinned per XCD,
// lockstep tn sweep -> A L2-resident per XCD, B L3-shared across XCDs) to
// kill the ~12x HBM re-fetch that made rounds 1-5 memory-bound
// (dur == hbm_bytes/hbm_gbps every round). Loop/sync identical to round 5.
// ws: [0,64MiB) Xbf, [64MiB,192MiB) WTbf.
// ---------------------------------------------------------------------------

namespace {

constexpr int MD = 8192;    // B*T
constexpr int ND = 16384;   // F
constexpr int KD = 4096;    // D
constexpr int NT = KD / 64; // 64 k-tiles of BK=64

typedef __bf16 bf16x8 __attribute__((ext_vector_type(8)));
typedef float  f32x4  __attribute__((ext_vector_type(4)));
typedef float  fl4    __attribute__((ext_vector_type(4)));
typedef unsigned int u32x4 __attribute__((ext_vector_type(4)));

__device__ __forceinline__ unsigned int f2bf(float f) {
  unsigned int u = __float_as_uint(f);
  return (u + 0x7FFFu + ((u >> 16) & 1u)) >> 16;
}

// ---- x fp32 [M][K] -> bf16 [M][K] ----------------------------------------
__global__ __launch_bounds__(256) void convert_x_kernel(
    const float* __restrict__ x, unsigned short* __restrict__ xb) {
  size_t i = ((size_t)blockIdx.x * 256 + threadIdx.x) * 8;
  fl4 a = *(const fl4*)(x + i);
  fl4 b = *(const fl4*)(x + i + 4);
  u32x4 o;
  o.x = f2bf(a.x) | (f2bf(a.y) << 16);
  o.y = f2bf(a.z) | (f2bf(a.w) << 16);
  o.z = f2bf(b.x) | (f2bf(b.y) << 16);
  o.w = f2bf(b.z) | (f2bf(b.w) << 16);
  *(u32x4*)(xb + i) = o;
}

// ---- W int32 [K][N] -> bf16 W^T [N][K] ------------------------------------
__global__ __launch_bounds__(256) void transpose_w_kernel(
    const int* __restrict__ W, unsigned short* __restrict__ WT) {
  constexpr int KC = 64;
  const int nb = blockIdx.x & 63;
  const int kb = blockIdx.x >> 6;
  const int n  = nb * 256 + threadIdx.x;
  const int k0 = kb * KC;

  unsigned int buf[KC / 2];
  const int* src = W + (size_t)k0 * ND + n;
#pragma unroll
  for (int i = 0; i < KC; i += 2) {
    int v0 = src[(size_t)i * ND];
    int v1 = src[(size_t)(i + 1) * ND];
    buf[i >> 1] = f2bf((float)v0) | (f2bf((float)v1) << 16);
  }
  u32x4* dst = (u32x4*)(WT + (size_t)n * KD + k0);
#pragma unroll
  for (int j = 0; j < KC / 8; ++j) {
    u32x4 o;
    o.x = buf[4 * j + 0];
    o.y = buf[4 * j + 1];
    o.z = buf[4 * j + 2];
    o.w = buf[4 * j + 3];
    dst[j] = o;
  }
}

// ---- 256x256 GEMM ---------------------------------------------------------

#define GLL16(g, l)                                                  \
  __builtin_amdgcn_global_load_lds(                                  \
      (const __attribute__((address_space(1))) void*)(g),            \
      (__attribute__((address_space(3))) void*)(l), 16, 0, 0)

#define BARRIER()    __builtin_amdgcn_s_barrier()
#define WAITL(N)     asm volatile("s_waitcnt lgkmcnt(" #N ")")
#define WAITV8()     asm volatile("s_waitcnt vmcnt(8)")
#define SCHED()      __builtin_amdgcn_sched_barrier(0)
#define PRIO1()      __builtin_amdgcn_s_setprio(1)
#define PRIO0()      __builtin_amdgcn_s_setprio(0)

// one "half-tile" = 128 rows x 64 bf16 (16 KB) = 2 global_load_lds per wave.
// LDS dest is linear; source col is pre-swizzled (rule #21) so that
// LDS[row][col'] = G[row][col' ^ ((row&7)<<4 bytes)].
__device__ __forceinline__ void stage_half(const unsigned short* g0,
                                           unsigned short* lbase, int w) {
  char* l = (char*)lbase + w * 1024;
  GLL16(g0, l);
  GLL16(g0 + (size_t)64 * KD, l + 8192);
}

// ds_read of one MFMA A/B fragment with the read-side swizzle
#define RD_A(DST, MOFF)                                                       \
  _Pragma("unroll") for (int mi = 0; mi < 4; ++mi)                            \
  _Pragma("unroll") for (int kk = 0; kk < 2; ++kk)                            \
      DST[mi][kk] = *(const bf16x8*)(Ard + (size_t)((MOFF + mi) * 16 + r15) * \
                                               128 +                          \
                                     ((kk * 64 + hi16) ^ sw16));

#define RD_B(DST, NOFF)                                                       \
  _Pragma("unroll") for (int ni = 0; ni < 2; ++ni)                            \
  _Pragma("unroll") for (int kk = 0; kk < 2; ++kk)                            \
      DST[ni][kk] = *(const bf16x8*)(Brd + (size_t)((NOFF + ni) * 16 + r15) * \
                                               128 +                          \
                                     ((kk * 64 + hi16) ^ sw16));

#define QUAD(AARR, BARR, MB, NB)                                              \
  _Pragma("unroll") for (int mi = 0; mi < 4; ++mi)                            \
  _Pragma("unroll") for (int ni = 0; ni < 2; ++ni)                            \
  _Pragma("unroll") for (int kk = 0; kk < 2; ++kk)                            \
      acc[MB + mi][NB + ni] = __builtin_amdgcn_mfma_f32_16x16x32_bf16(        \
          AARR[mi][kk], BARR[ni][kk], acc[MB + mi][NB + ni], 0, 0, 0);

__global__ __launch_bounds__(512, 2) void gemm_kernel(
    const unsigned short* __restrict__ A,   // bf16 [M][K]
    const unsigned short* __restrict__ Bt,  // bf16 [N][K]
    const float* __restrict__ scale,        // [N]
    float* __restrict__ C) {                // f32 [M][N]
  // [buf][256 rows][64 bf16]; half0 = rows 0-127, half1 = rows 128-255
  __shared__ __align__(16) unsigned short Asmem[2][16384];
  __shared__ __align__(16) unsigned short Bsmem[2][16384];

  const int tid  = threadIdx.x;
  const int lane = tid & 63;
  const int w    = tid >> 6;   // wave 0..7
  const int wm   = w >> 2;     // 0..1 : owns A rows wm*128..+127
  const int wn   = w & 3;      // 0..3 : owns B cols wn*64..+63

  // 2D XCD supertiling: XCD c (== bid&7, round-robin dispatch) owns A
  // row-band tm in [4c, 4c+4) for the WHOLE kernel (8 MB, L2/L3-hot) and
  // sweeps tn with tm-fastest in-chunk order, so its 32 concurrent blocks
  // form a 4tm x 8tn window: A K-slices 8-way L2-shared, B K-slices 4-way
  // L2-shared per XCD and 8-way L3-shared across XCDs (lockstep tn sweep).
  const int bid = blockIdx.x;            // 2048 = 8 XCD chunks x 256
  const int xcd = bid & 7;
  const int pos = bid >> 3;              // 0..255: in-chunk dispatch order
  const int tm  = (xcd << 2) | (pos & 3);   // 0..31
  const int tn  = pos >> 2;                 // 0..63
  const size_t brow = (size_t)tm * 256;
  const size_t bcol = (size_t)tn * 256;

  // staging source addressing (pre-swizzled col, see stage_half)
  const int srow = w * 8 + (lane >> 3);                        // 0..63
  const int scol = (((lane & 7) ^ ((lane >> 3) & 7)) << 3);    // elems
  const unsigned short* Ag = A  + (brow + srow) * (size_t)KD + scol;
  const unsigned short* Bg = Bt + (bcol + srow) * (size_t)KD + scol;

  // fragment-read addressing
  const int r15  = lane & 15;
  const int hi16 = (lane >> 4) << 4;   // byte col within row
  const int sw16 = (lane & 7) << 4;    // read-side swizzle XOR

  f32x4 acc[8][4];
  const f32x4 z = {0.f, 0.f, 0.f, 0.f};
#pragma unroll
  for (int i = 0; i < 8; ++i)
#pragma unroll
    for (int j = 0; j < 4; ++j) acc[i][j] = z;

  // ---- prologue: tiles 0 and 1 staged; tile1's 8 loads stay in flight ----
  stage_half(Ag,                          &Asmem[0][0],    w);
  stage_half(Ag + (size_t)128 * KD,       &Asmem[0][8192], w);
  stage_half(Bg,                          &Bsmem[0][0],    w);
  stage_half(Bg + (size_t)128 * KD,       &Bsmem[0][8192], w);
  stage_half(Ag + 64,                     &Asmem[1][0],    w);
  stage_half(Ag + (size_t)128 * KD + 64,  &Asmem[1][8192], w);
  stage_half(Bg + 64,                     &Bsmem[1][0],    w);
  stage_half(Bg + (size_t)128 * KD + 64,  &Bsmem[1][8192], w);
  SCHED();
  WAITV8();  // tile0 resident; tile1's 8 loads in flight
  SCHED();
  BARRIER();

  bf16x8 aL[4][2], aH[4][2], bL[2][2], bH[2][2];

  // ---- main loop: 64 K-tiles ----
#pragma unroll 2
  for (int it = 0; it < NT; ++it) {
    const int h = it & 1;
    const char* Ard = (const char*)&Asmem[h][0] + wm * 16384;
    const char* Brd = (const char*)&Bsmem[h][0] + wn * 8192;
    const size_t kb2 = (size_t)((it + 2) & (NT - 1)) * 64;
    unsigned short* Adst = &Asmem[h][0];
    unsigned short* Bdst = &Bsmem[h][0];

    // issue Q0's 12 reads first (in-order DS returns -> lgkm(12) = aL,bL)
    RD_A(aL, 0);
    RD_B(bL, 0);
    SCHED();
    RD_A(aH, 4);
    RD_B(bH, 2);
    SCHED();
    WAITL(12);   // aL,bL resident
    SCHED();
    PRIO1();
    QUAD(aL, bL, 0, 0);   // 16 MFMA cover the drain of the remaining 12 reads
    PRIO0();
    SCHED();
    WAITL(0);    // all my reads of buf h physically complete
    SCHED();
    PRIO1();
    QUAD(aH, bL, 4, 0);
    QUAD(aH, bH, 4, 2);
    QUAD(aL, bH, 0, 2);
    PRIO0();
    SCHED();
    BARRIER();   // cross-wave: buf h fully read by everyone -> safe to restage
    SCHED();
    stage_half(Ag + kb2,                    Adst, w);
    stage_half(Bg + kb2,                    Bdst, w);
    stage_half(Ag + (size_t)128 * KD + kb2, Adst + 8192, w);
    stage_half(Bg + (size_t)128 * KD + kb2, Bdst + 8192, w);
    SCHED();
    WAITV8();    // drain tile(it+1)'s 8 loads; keep tile(it+2)'s in flight
    SCHED();
    BARRIER();   // buf h^1 (tile it+1) certified for next iteration
  }

  // ---- epilogue: acc * (1/scale[col]) -> C ----
  const int r4 = (lane >> 4) << 2;
#pragma unroll
  for (int ni = 0; ni < 4; ++ni) {
    const size_t col = bcol + wn * 64 + ni * 16 + r15;
    const float inv = 1.0f / scale[col];
#pragma unroll
    for (int mi = 0; mi < 8; ++mi) {
      float* cp = C + (brow + wm * 128 + mi * 16 + r4) * (size_t)ND + col;
#pragma unroll
      for (int r = 0; r < 4; ++r) cp[(size_t)r * ND] = acc[mi][ni][r] * inv;
    }
  }
}

}  // namespace

extern "C" void kernel_launch(void* const* d_in, const int* in_sizes, int n_in,
                              void* d_out, int out_size, void* d_ws,
                              size_t ws_size, hipStream_t stream) {
  const float* x     = (const float*)d_in[0];
  const int*   W     = (const int*)d_in[1];
  const float* scale = (const float*)d_in[2];
  float*       out   = (float*)d_out;

  unsigned short* xb = (unsigned short*)d_ws;
  unsigned short* wt = (unsigned short*)((char*)d_ws + (size_t)MD * KD * 2);

  convert_x_kernel<<<16384, 256, 0, stream>>>(x, xb);
  transpose_w_kernel<<<4096, 256, 0, stream>>>(W, wt);
  gemm_kernel<<<2048, 512, 0, stream>>>(xb, wt, scale, out);
}

// Round 7
// 1284.989 us; speedup vs baseline: 1.2107x; 1.0409x over previous
//
#include <hip/hip_runtime.h>

// ---------------------------------------------------------------------------
// out[b,t,f] = sum_d x[b,t,d] * (W[d,f] / scale[f])
// GEMM: M=8192 (B*T), K=4096 (D), N=16384 (F)
// x->bf16 (ws), W int -> bf16 W^T (ws), then 256x256-tile bf16 MFMA GEMM.
// Round 7: m201 4-phase-per-K-tile interleave — each phase = {ds_read burst
// and/or stage} + barrier + lgkm(0) + setprio MFMA quadrant + barrier, with
// counted vmcnt(8) once per tile (never 0). Supertile grid + T2 swizzle
// unchanged from round 6. ws: [0,64MiB) Xbf, [64MiB,192MiB) WTbf.
// ---------------------------------------------------------------------------

namespace {

constexpr int MD = 8192;    // B*T
constexpr int ND = 16384;   // F
constexpr int KD = 4096;    // D
constexpr int NT = KD / 64; // 64 k-tiles of BK=64

typedef __bf16 bf16x8 __attribute__((ext_vector_type(8)));
typedef float  f32x4  __attribute__((ext_vector_type(4)));
typedef float  fl4    __attribute__((ext_vector_type(4)));
typedef unsigned int u32x4 __attribute__((ext_vector_type(4)));

__device__ __forceinline__ unsigned int f2bf(float f) {
  unsigned int u = __float_as_uint(f);
  return (u + 0x7FFFu + ((u >> 16) & 1u)) >> 16;
}

// ---- x fp32 [M][K] -> bf16 [M][K] ----------------------------------------
__global__ __launch_bounds__(256) void convert_x_kernel(
    const float* __restrict__ x, unsigned short* __restrict__ xb) {
  size_t i = ((size_t)blockIdx.x * 256 + threadIdx.x) * 8;
  fl4 a = *(const fl4*)(x + i);
  fl4 b = *(const fl4*)(x + i + 4);
  u32x4 o;
  o.x = f2bf(a.x) | (f2bf(a.y) << 16);
  o.y = f2bf(a.z) | (f2bf(a.w) << 16);
  o.z = f2bf(b.x) | (f2bf(b.y) << 16);
  o.w = f2bf(b.z) | (f2bf(b.w) << 16);
  *(u32x4*)(xb + i) = o;
}

// ---- W int32 [K][N] -> bf16 W^T [N][K] ------------------------------------
__global__ __launch_bounds__(256) void transpose_w_kernel(
    const int* __restrict__ W, unsigned short* __restrict__ WT) {
  constexpr int KC = 64;
  const int nb = blockIdx.x & 63;
  const int kb = blockIdx.x >> 6;
  const int n  = nb * 256 + threadIdx.x;
  const int k0 = kb * KC;

  unsigned int buf[KC / 2];
  const int* src = W + (size_t)k0 * ND + n;
#pragma unroll
  for (int i = 0; i < KC; i += 2) {
    int v0 = src[(size_t)i * ND];
    int v1 = src[(size_t)(i + 1) * ND];
    buf[i >> 1] = f2bf((float)v0) | (f2bf((float)v1) << 16);
  }
  u32x4* dst = (u32x4*)(WT + (size_t)n * KD + k0);
#pragma unroll
  for (int j = 0; j < KC / 8; ++j) {
    u32x4 o;
    o.x = buf[4 * j + 0];
    o.y = buf[4 * j + 1];
    o.z = buf[4 * j + 2];
    o.w = buf[4 * j + 3];
    dst[j] = o;
  }
}

// ---- 256x256 GEMM ---------------------------------------------------------

#define GLL16(g, l)                                                  \
  __builtin_amdgcn_global_load_lds(                                  \
      (const __attribute__((address_space(1))) void*)(g),            \
      (__attribute__((address_space(3))) void*)(l), 16, 0, 0)

#define BARRIER()    __builtin_amdgcn_s_barrier()
#define WAITL0()     asm volatile("s_waitcnt lgkmcnt(0)")
#define WAITV8()     asm volatile("s_waitcnt vmcnt(8)")
#define SCHED()      __builtin_amdgcn_sched_barrier(0)
#define PRIO1()      __builtin_amdgcn_s_setprio(1)
#define PRIO0()      __builtin_amdgcn_s_setprio(0)

// one "half-tile" = 128 rows x 64 bf16 (16 KB) = 2 global_load_lds per wave.
// LDS dest is linear; source col is pre-swizzled (rule #21) so that
// LDS[row][col'] = G[row][col' ^ ((row&7)<<4 bytes)].
__device__ __forceinline__ void stage_half(const unsigned short* g0,
                                           unsigned short* lbase, int w) {
  char* l = (char*)lbase + w * 1024;
  GLL16(g0, l);
  GLL16(g0 + (size_t)64 * KD, l + 8192);
}

// ds_read of one MFMA A/B fragment with the read-side swizzle
#define RD_A(DST, MOFF)                                                       \
  _Pragma("unroll") for (int mi = 0; mi < 4; ++mi)                            \
  _Pragma("unroll") for (int kk = 0; kk < 2; ++kk)                            \
      DST[mi][kk] = *(const bf16x8*)(Ard + (size_t)((MOFF + mi) * 16 + r15) * \
                                               128 +                          \
                                     ((kk * 64 + hi16) ^ sw16));

#define RD_B(DST, NOFF)                                                       \
  _Pragma("unroll") for (int ni = 0; ni < 2; ++ni)                            \
  _Pragma("unroll") for (int kk = 0; kk < 2; ++kk)                            \
      DST[ni][kk] = *(const bf16x8*)(Brd + (size_t)((NOFF + ni) * 16 + r15) * \
                                               128 +                          \
                                     ((kk * 64 + hi16) ^ sw16));

#define QUAD(AARR, BARR, MB, NB)                                              \
  _Pragma("unroll") for (int mi = 0; mi < 4; ++mi)                            \
  _Pragma("unroll") for (int ni = 0; ni < 2; ++ni)                            \
  _Pragma("unroll") for (int kk = 0; kk < 2; ++kk)                            \
      acc[MB + mi][NB + ni] = __builtin_amdgcn_mfma_f32_16x16x32_bf16(        \
          AARR[mi][kk], BARR[ni][kk], acc[MB + mi][NB + ni], 0, 0, 0);

__global__ __launch_bounds__(512, 2) void gemm_kernel(
    const unsigned short* __restrict__ A,   // bf16 [M][K]
    const unsigned short* __restrict__ Bt,  // bf16 [N][K]
    const float* __restrict__ scale,        // [N]
    float* __restrict__ C) {                // f32 [M][N]
  // [buf][256 rows][64 bf16]; half0 = rows 0-127, half1 = rows 128-255
  __shared__ __align__(16) unsigned short Asmem[2][16384];
  __shared__ __align__(16) unsigned short Bsmem[2][16384];

  const int tid  = threadIdx.x;
  const int lane = tid & 63;
  const int w    = tid >> 6;   // wave 0..7
  const int wm   = w >> 2;     // 0..1 : owns A rows wm*128..+127
  const int wn   = w & 3;      // 0..3 : owns B cols wn*64..+63

  // 2D XCD supertiling (round 6): XCD c owns A row-band tm in [4c,4c+4),
  // sweeps tn with tm-fastest order -> A L2-resident per XCD, B L3-shared.
  const int bid = blockIdx.x;            // 2048 = 8 XCD chunks x 256
  const int xcd = bid & 7;
  const int pos = bid >> 3;              // 0..255: in-chunk dispatch order
  const int tm  = (xcd << 2) | (pos & 3);   // 0..31
  const int tn  = pos >> 2;                 // 0..63
  const size_t brow = (size_t)tm * 256;
  const size_t bcol = (size_t)tn * 256;

  // staging source addressing (pre-swizzled col, see stage_half)
  const int srow = w * 8 + (lane >> 3);                        // 0..63
  const int scol = (((lane & 7) ^ ((lane >> 3) & 7)) << 3);    // elems
  const unsigned short* Ag = A  + (brow + srow) * (size_t)KD + scol;
  const unsigned short* Bg = Bt + (bcol + srow) * (size_t)KD + scol;

  // fragment-read addressing
  const int r15  = lane & 15;
  const int hi16 = (lane >> 4) << 4;   // byte col within row
  const int sw16 = (lane & 7) << 4;    // read-side swizzle XOR

  f32x4 acc[8][4];
  const f32x4 z = {0.f, 0.f, 0.f, 0.f};
#pragma unroll
  for (int i = 0; i < 8; ++i)
#pragma unroll
    for (int j = 0; j < 4; ++j) acc[i][j] = z;

  // ---- prologue: tiles 0 and 1 staged; tile1's 8 loads stay in flight ----
  stage_half(Ag,                          &Asmem[0][0],    w);
  stage_half(Ag + (size_t)128 * KD,       &Asmem[0][8192], w);
  stage_half(Bg,                          &Bsmem[0][0],    w);
  stage_half(Bg + (size_t)128 * KD,       &Bsmem[0][8192], w);
  stage_half(Ag + 64,                     &Asmem[1][0],    w);
  stage_half(Ag + (size_t)128 * KD + 64,  &Asmem[1][8192], w);
  stage_half(Bg + 64,                     &Bsmem[1][0],    w);
  stage_half(Bg + (size_t)128 * KD + 64,  &Bsmem[1][8192], w);
  SCHED();
  WAITV8();  // tile0 resident; tile1's 8 loads in flight
  SCHED();
  BARRIER();
  SCHED();

  bf16x8 aL[4][2], aH[4][2], bL[2][2], bH[2][2];

  // ---- main loop: 64 K-tiles, 4 phases each ----
#pragma unroll 2
  for (int it = 0; it < NT; ++it) {
    const int h = it & 1;
    const char* Ard = (const char*)&Asmem[h][0] + wm * 16384;
    const char* Brd = (const char*)&Bsmem[h][0] + wn * 8192;
    const size_t kb2 = (size_t)((it + 2) & (NT - 1)) * 64;
    unsigned short* Adst = &Asmem[h][0];
    unsigned short* Bdst = &Bsmem[h][0];

    // P1: read aL+bL (12 b128) ; Q00
    RD_A(aL, 0);
    RD_B(bL, 0);
    SCHED(); BARRIER(); SCHED();
    WAITL0();
    SCHED();
    PRIO1();
    QUAD(aL, bL, 0, 0);
    PRIO0();
    SCHED(); BARRIER(); SCHED();

    // P2: read aH+bH (12 b128) ; Q10. After the trailing barrier, every
    // wave's 24 reads of buf h are complete -> buf h free for restaging.
    RD_A(aH, 4);
    RD_B(bH, 2);
    SCHED(); BARRIER(); SCHED();
    WAITL0();
    SCHED();
    PRIO1();
    QUAD(aH, bL, 4, 0);
    PRIO0();
    SCHED(); BARRIER(); SCHED();

    // P3: stage tile(it+2) A halves ; Q11
    stage_half(Ag + kb2,                    Adst, w);
    stage_half(Ag + (size_t)128 * KD + kb2, Adst + 8192, w);
    SCHED();
    PRIO1();
    QUAD(aH, bH, 4, 2);
    PRIO0();
    SCHED(); BARRIER(); SCHED();

    // P4: stage tile(it+2) B halves ; Q01 ; counted vmcnt(8) certifies
    // tile(it+1) (4-5 phases old), keeps tile(it+2)'s 8 in flight.
    stage_half(Bg + kb2,                    Bdst, w);
    stage_half(Bg + (size_t)128 * KD + kb2, Bdst + 8192, w);
    SCHED();
    PRIO1();
    QUAD(aL, bH, 0, 2);
    PRIO0();
    SCHED();
    WAITV8();
    SCHED(); BARRIER(); SCHED();
  }

  // ---- epilogue: acc * (1/scale[col]) -> C ----
  const int r4 = (lane >> 4) << 2;
#pragma unroll
  for (int ni = 0; ni < 4; ++ni) {
    const size_t col = bcol + wn * 64 + ni * 16 + r15;
    const float inv = 1.0f / scale[col];
#pragma unroll
    for (int mi = 0; mi < 8; ++mi) {
      float* cp = C + (brow + wm * 128 + mi * 16 + r4) * (size_t)ND + col;
#pragma unroll
      for (int r = 0; r < 4; ++r) cp[(size_t)r * ND] = acc[mi][ni][r] * inv;
    }
  }
}

}  // namespace

extern "C" void kernel_launch(void* const* d_in, const int* in_sizes, int n_in,
                              void* d_out, int out_size, void* d_ws,
                              size_t ws_size, hipStream_t stream) {
  const float* x     = (const float*)d_in[0];
  const int*   W     = (const int*)d_in[1];
  const float* scale = (const float*)d_in[2];
  float*       out   = (float*)d_out;

  unsigned short* xb = (unsigned short*)d_ws;
  unsigned short* wt = (unsigned short*)((char*)d_ws + (size_t)MD * KD * 2);

  convert_x_kernel<<<16384, 256, 0, stream>>>(x, xb);
  transpose_w_kernel<<<4096, 256, 0, stream>>>(W, wt);
  gemm_kernel<<<2048, 512, 0, stream>>>(xb, wt, scale, out);
}

// Round 8
// 1173.195 us; speedup vs baseline: 1.3260x; 1.0953x over previous
//
#include <hip/hip_runtime.h>

// ---------------------------------------------------------------------------
// out[b,t,f] = sum_d x[b,t,d] * (W[d,f] / scale[f])
// GEMM: M=8192 (B*T), K=4096 (D), N=16384 (F)
// x->bf16 (ws), W int -> bf16 W^T (ws), 256x256-tile bf16 MFMA GEMM.
// Round 8: cross-phase read pipelining — every lgkmcnt wait certifies a
// cluster issued one phase EARLIER (its drain hidden under the intervening
// MFMA cluster); aL is prefetched from the next buffer during Ph2 into
// dead registers, so no VGPR double-buffering. vmcnt(0) is placed where
// nothing newer is in flight (issue-early/certify-late). 2 barriers/K-tile.
// Supertile grid + T2 swizzle unchanged. ws: [0,64MiB) Xbf, [64MiB,192MiB) WT.
// ---------------------------------------------------------------------------

namespace {

constexpr int MD = 8192;    // B*T
constexpr int ND = 16384;   // F
constexpr int KD = 4096;    // D
constexpr int NT = KD / 64; // 64 k-tiles of BK=64

typedef __bf16 bf16x8 __attribute__((ext_vector_type(8)));
typedef float  f32x4  __attribute__((ext_vector_type(4)));
typedef float  fl4    __attribute__((ext_vector_type(4)));
typedef unsigned int u32x4 __attribute__((ext_vector_type(4)));

__device__ __forceinline__ unsigned int f2bf(float f) {
  unsigned int u = __float_as_uint(f);
  return (u + 0x7FFFu + ((u >> 16) & 1u)) >> 16;
}

// ---- x fp32 [M][K] -> bf16 [M][K] ----------------------------------------
__global__ __launch_bounds__(256) void convert_x_kernel(
    const float* __restrict__ x, unsigned short* __restrict__ xb) {
  size_t i = ((size_t)blockIdx.x * 256 + threadIdx.x) * 8;
  fl4 a = *(const fl4*)(x + i);
  fl4 b = *(const fl4*)(x + i + 4);
  u32x4 o;
  o.x = f2bf(a.x) | (f2bf(a.y) << 16);
  o.y = f2bf(a.z) | (f2bf(a.w) << 16);
  o.z = f2bf(b.x) | (f2bf(b.y) << 16);
  o.w = f2bf(b.z) | (f2bf(b.w) << 16);
  *(u32x4*)(xb + i) = o;
}

// ---- W int32 [K][N] -> bf16 W^T [N][K] ------------------------------------
__global__ __launch_bounds__(256) void transpose_w_kernel(
    const int* __restrict__ W, unsigned short* __restrict__ WT) {
  constexpr int KC = 64;
  const int nb = blockIdx.x & 63;
  const int kb = blockIdx.x >> 6;
  const int n  = nb * 256 + threadIdx.x;
  const int k0 = kb * KC;

  unsigned int buf[KC / 2];
  const int* src = W + (size_t)k0 * ND + n;
#pragma unroll
  for (int i = 0; i < KC; i += 2) {
    int v0 = src[(size_t)i * ND];
    int v1 = src[(size_t)(i + 1) * ND];
    buf[i >> 1] = f2bf((float)v0) | (f2bf((float)v1) << 16);
  }
  u32x4* dst = (u32x4*)(WT + (size_t)n * KD + k0);
#pragma unroll
  for (int j = 0; j < KC / 8; ++j) {
    u32x4 o;
    o.x = buf[4 * j + 0];
    o.y = buf[4 * j + 1];
    o.z = buf[4 * j + 2];
    o.w = buf[4 * j + 3];
    dst[j] = o;
  }
}

// ---- 256x256 GEMM ---------------------------------------------------------

#define GLL16(g, l)                                                  \
  __builtin_amdgcn_global_load_lds(                                  \
      (const __attribute__((address_space(1))) void*)(g),            \
      (__attribute__((address_space(3))) void*)(l), 16, 0, 0)

#define BARRIER()    __builtin_amdgcn_s_barrier()
#define WAITL(N)     asm volatile("s_waitcnt lgkmcnt(" #N ")")
#define WAITV(N)     asm volatile("s_waitcnt vmcnt(" #N ")")
#define SCHED()      __builtin_amdgcn_sched_barrier(0)
#define PRIO1()      __builtin_amdgcn_s_setprio(1)
#define PRIO0()      __builtin_amdgcn_s_setprio(0)

// one "half-tile" = 128 rows x 64 bf16 (16 KB) = 2 global_load_lds per wave.
// LDS dest linear; source col pre-swizzled (rule #21):
// LDS[row][col'] = G[row][col' ^ ((row&7)<<4 bytes)].
__device__ __forceinline__ void stage_half(const unsigned short* g0,
                                           unsigned short* lbase, int w) {
  char* l = (char*)lbase + w * 1024;
  GLL16(g0, l);
  GLL16(g0 + (size_t)64 * KD, l + 8192);
}

// fragment ds_reads with read-side swizzle; base passed explicitly
#define RD_A(BASE, DST, MOFF)                                                 \
  _Pragma("unroll") for (int mi = 0; mi < 4; ++mi)                            \
  _Pragma("unroll") for (int kk = 0; kk < 2; ++kk)                            \
      DST[mi][kk] = *(const bf16x8*)(BASE +                                   \
                                     (size_t)((MOFF + mi) * 16 + r15) * 128 + \
                                     ((kk * 64 + hi16) ^ sw16));

#define RD_B(BASE, DST, NOFF)                                                 \
  _Pragma("unroll") for (int ni = 0; ni < 2; ++ni)                            \
  _Pragma("unroll") for (int kk = 0; kk < 2; ++kk)                            \
      DST[ni][kk] = *(const bf16x8*)(BASE +                                   \
                                     (size_t)((NOFF + ni) * 16 + r15) * 128 + \
                                     ((kk * 64 + hi16) ^ sw16));

#define QUAD(AARR, BARR, MB, NB)                                              \
  _Pragma("unroll") for (int mi = 0; mi < 4; ++mi)                            \
  _Pragma("unroll") for (int ni = 0; ni < 2; ++ni)                            \
  _Pragma("unroll") for (int kk = 0; kk < 2; ++kk)                            \
      acc[MB + mi][NB + ni] = __builtin_amdgcn_mfma_f32_16x16x32_bf16(        \
          AARR[mi][kk], BARR[ni][kk], acc[MB + mi][NB + ni], 0, 0, 0);

__global__ __launch_bounds__(512, 2) void gemm_kernel(
    const unsigned short* __restrict__ A,   // bf16 [M][K]
    const unsigned short* __restrict__ Bt,  // bf16 [N][K]
    const float* __restrict__ scale,        // [N]
    float* __restrict__ C) {                // f32 [M][N]
  __shared__ __align__(16) unsigned short Asmem[2][16384];
  __shared__ __align__(16) unsigned short Bsmem[2][16384];

  const int tid  = threadIdx.x;
  const int lane = tid & 63;
  const int w    = tid >> 6;   // wave 0..7
  const int wm   = w >> 2;     // 0..1
  const int wn   = w & 3;      // 0..3

  // 2D XCD supertiling (round 6)
  const int bid = blockIdx.x;            // 2048 = 8 XCD chunks x 256
  const int xcd = bid & 7;
  const int pos = bid >> 3;
  const int tm  = (xcd << 2) | (pos & 3);   // 0..31
  const int tn  = pos >> 2;                 // 0..63
  const size_t brow = (size_t)tm * 256;
  const size_t bcol = (size_t)tn * 256;

  const int srow = w * 8 + (lane >> 3);
  const int scol = (((lane & 7) ^ ((lane >> 3) & 7)) << 3);
  const unsigned short* Ag = A  + (brow + srow) * (size_t)KD + scol;
  const unsigned short* Bg = Bt + (bcol + srow) * (size_t)KD + scol;

  const int r15  = lane & 15;
  const int hi16 = (lane >> 4) << 4;
  const int sw16 = (lane & 7) << 4;

  f32x4 acc[8][4];
  const f32x4 z = {0.f, 0.f, 0.f, 0.f};
#pragma unroll
  for (int i = 0; i < 8; ++i)
#pragma unroll
    for (int j = 0; j < 4; ++j) acc[i][j] = z;

  // ---- prologue ----
  stage_half(Ag,                          &Asmem[0][0],    w);
  stage_half(Ag + (size_t)128 * KD,       &Asmem[0][8192], w);
  stage_half(Bg,                          &Bsmem[0][0],    w);
  stage_half(Bg + (size_t)128 * KD,       &Bsmem[0][8192], w);
  stage_half(Ag + 64,                     &Asmem[1][0],    w);
  stage_half(Ag + (size_t)128 * KD + 64,  &Asmem[1][8192], w);
  stage_half(Bg + 64,                     &Bsmem[1][0],    w);
  stage_half(Bg + (size_t)128 * KD + 64,  &Bsmem[1][8192], w);
  SCHED();
  WAITV(8);   // tile0 resident; tile1's 8 loads in flight
  SCHED();
  BARRIER();
  SCHED();

  bf16x8 aL[4][2], aH[4][2], bL[2][2], bH[2][2];

  // prime the pipeline: aL of tile0
  {
    const char* Ard0 = (const char*)&Asmem[0][0] + wm * 16384;
    RD_A(Ard0, aL, 0);   // 8 reads, drain under Ph1 issue window
  }
  SCHED();

  // ---- main loop: 64 K-tiles, cross-phase pipelined ----
#pragma unroll 2
  for (int it = 0; it < NT; ++it) {
    const int h = it & 1;
    const char* Ard  = (const char*)&Asmem[h][0]     + wm * 16384;
    const char* ArdN = (const char*)&Asmem[h ^ 1][0] + wm * 16384;
    const char* Brd  = (const char*)&Bsmem[h][0] + wn * 8192;
    const size_t kb2 = (size_t)((it + 2) & (NT - 1)) * 64;

    // ---- Ph1 ----
    RD_B(Brd, bL, 0);            // 4 reads (oldest of this burst)
    SCHED();
    RD_B(Brd, bH, 2);            // 4 reads
    SCHED();
    RD_A(Ard, aH, 4);            // 8 reads
    SCHED();
    WAITL(12);                   // aL (prefetched) + bL done; bH,aH in flight
    SCHED();
    PRIO1();
    QUAD(aL, bL, 0, 0);          // 16 MFMA cover bH/aH drain
    PRIO0();
    SCHED();
    WAITL(8);                    // bH done; aH in flight
    SCHED();
    PRIO1();
    QUAD(aL, bH, 0, 2);          // 16 MFMA cover aH drain; aL dies here
    PRIO0();
    SCHED();

    // ---- Ph2 ----
    WAITV(0);    // tile it+1 resident in buf[h^1] (loads issued 1 K-tile ago;
                 // nothing newer in flight -> free, no depth lost)
    SCHED();
    BARRIER();   // RAW: all waves' staging of buf[h^1] certified
    SCHED();
    RD_A(ArdN, aL, 0);           // prefetch aL of tile it+1 (dead regs)
    SCHED();
    WAITL(8);                    // aH done; aL' in flight
    SCHED();
    BARRIER();   // WAR: all waves' reads of buf[h] complete
    SCHED();
    stage_half(Ag + kb2,                    &Asmem[h][0],    w);
    stage_half(Ag + (size_t)128 * KD + kb2, &Asmem[h][8192], w);
    stage_half(Bg + kb2,                    &Bsmem[h][0],    w);
    stage_half(Bg + (size_t)128 * KD + kb2, &Bsmem[h][8192], w);
    SCHED();
    PRIO1();
    QUAD(aH, bL, 4, 0);          // 32 MFMA cover aL' drain + stage flight
    QUAD(aH, bH, 4, 2);
    PRIO0();
    SCHED();
  }

  // ---- epilogue: acc * (1/scale[col]) -> C ----
  const int r4 = (lane >> 4) << 2;
#pragma unroll
  for (int ni = 0; ni < 4; ++ni) {
    const size_t col = bcol + wn * 64 + ni * 16 + r15;
    const float inv = 1.0f / scale[col];
#pragma unroll
    for (int mi = 0; mi < 8; ++mi) {
      float* cp = C + (brow + wm * 128 + mi * 16 + r4) * (size_t)ND + col;
#pragma unroll
      for (int r = 0; r < 4; ++r) cp[(size_t)r * ND] = acc[mi][ni][r] * inv;
    }
  }
}

}  // namespace

extern "C" void kernel_launch(void* const* d_in, const int* in_sizes, int n_in,
                              void* d_out, int out_size, void* d_ws,
                              size_t ws_size, hipStream_t stream) {
  const float* x     = (const float*)d_in[0];
  const int*   W     = (const int*)d_in[1];
  const float* scale = (const float*)d_in[2];
  float*       out   = (float*)d_out;

  unsigned short* xb = (unsigned short*)d_ws;
  unsigned short* wt = (unsigned short*)((char*)d_ws + (size_t)MD * KD * 2);

  convert_x_kernel<<<16384, 256, 0, stream>>>(x, xb);
  transpose_w_kernel<<<4096, 256, 0, stream>>>(W, wt);
  gemm_kernel<<<2048, 512, 0, stream>>>(xb, wt, scale, out);
}

// Round 9
// 840.452 us; speedup vs baseline: 1.8510x; 1.3959x over previous
//
#include <hip/hip_runtime.h>

// ---------------------------------------------------------------------------
// out[b,t,f] = sum_d x[b,t,d] * (W[d,f] / scale[f])
// GEMM: M=8192 (B*T), K=4096 (D), N=16384 (F)
// Round 9: int8 path. x -> per-row int8 (ws) + row scale; W -> int8 W^T (ws);
// 256x256-tile i8 MFMA GEMM (mfma_i32_16x16x64_i8, BK=64 = 1 K-step,
// 12 ds_read + 32 MFMA per wave per tile), R8 cross-phase schedule, granule
// swizzle (kc ^= (row>>1)&3, free 2-way), supertile grid. Epilogue:
// float(acc) * xrow_scale * (1/scale[col]). i32 accumulation is exact;
// x-quant error ~45 rms vs threshold 931.
// ws: [0,32M) xq int8 ; [32M,96M) WT int8 ; [96M,+32K) xs f32.
// ---------------------------------------------------------------------------

namespace {

constexpr int MD = 8192;    // B*T
constexpr int ND = 16384;   // F
constexpr int KD = 4096;    // D
constexpr int NT = KD / 64; // 64 k-tiles of BK=64

typedef float fl4 __attribute__((ext_vector_type(4)));
typedef unsigned int u32x4 __attribute__((ext_vector_type(4)));
typedef int i32x4 __attribute__((ext_vector_type(4)));

__device__ __forceinline__ unsigned int pack4(fl4 v, float sc) {
  int q0 = __float2int_rn(v.x * sc);
  int q1 = __float2int_rn(v.y * sc);
  int q2 = __float2int_rn(v.z * sc);
  int q3 = __float2int_rn(v.w * sc);
  return (q0 & 0xFF) | ((q1 & 0xFF) << 8) | ((q2 & 0xFF) << 16) |
         ((q3 & 0xFF) << 24);
}

// ---- x fp32 [M][K] -> int8 [M][K] + per-row scale -------------------------
__global__ __launch_bounds__(256) void quant_x_kernel(
    const float* __restrict__ x, signed char* __restrict__ xq,
    float* __restrict__ xs) {
  const int row = blockIdx.x;
  const int t   = threadIdx.x;
  const float* xr = x + (size_t)row * KD + t * 16;
  fl4 v0 = *(const fl4*)(xr);
  fl4 v1 = *(const fl4*)(xr + 4);
  fl4 v2 = *(const fl4*)(xr + 8);
  fl4 v3 = *(const fl4*)(xr + 12);
  float m = 0.f;
  m = fmaxf(m, fmaxf(fmaxf(fabsf(v0.x), fabsf(v0.y)), fmaxf(fabsf(v0.z), fabsf(v0.w))));
  m = fmaxf(m, fmaxf(fmaxf(fabsf(v1.x), fabsf(v1.y)), fmaxf(fabsf(v1.z), fabsf(v1.w))));
  m = fmaxf(m, fmaxf(fmaxf(fabsf(v2.x), fabsf(v2.y)), fmaxf(fabsf(v2.z), fabsf(v2.w))));
  m = fmaxf(m, fmaxf(fmaxf(fabsf(v3.x), fabsf(v3.y)), fmaxf(fabsf(v3.z), fabsf(v3.w))));
#pragma unroll
  for (int off = 32; off; off >>= 1) m = fmaxf(m, __shfl_xor(m, off));
  __shared__ float red[4];
  if ((t & 63) == 0) red[t >> 6] = m;
  __syncthreads();
  m = fmaxf(fmaxf(red[0], red[1]), fmaxf(red[2], red[3]));
  const float sc = (m > 0.f) ? 127.0f / m : 0.f;
  if (t == 0) xs[row] = (m > 0.f) ? m / 127.0f : 0.f;
  u32x4 o;
  o.x = pack4(v0, sc);
  o.y = pack4(v1, sc);
  o.z = pack4(v2, sc);
  o.w = pack4(v3, sc);
  *(u32x4*)(xq + (size_t)row * KD + t * 16) = o;
}

// ---- W int32 [K][N] -> int8 W^T [N][K] ------------------------------------
__global__ __launch_bounds__(256) void transpose_w_kernel(
    const int* __restrict__ W, signed char* __restrict__ WT) {
  constexpr int KC = 64;
  const int nb = blockIdx.x & 63;
  const int kb = blockIdx.x >> 6;
  const int n  = nb * 256 + threadIdx.x;
  const int k0 = kb * KC;
  const int* src = W + (size_t)k0 * ND + n;
  unsigned int buf[16];
#pragma unroll
  for (int i = 0; i < KC; i += 4) {
    unsigned int b0 = (unsigned)src[(size_t)(i + 0) * ND] & 0xFF;
    unsigned int b1 = (unsigned)src[(size_t)(i + 1) * ND] & 0xFF;
    unsigned int b2 = (unsigned)src[(size_t)(i + 2) * ND] & 0xFF;
    unsigned int b3 = (unsigned)src[(size_t)(i + 3) * ND] & 0xFF;
    buf[i >> 2] = b0 | (b1 << 8) | (b2 << 16) | (b3 << 24);
  }
  u32x4* dst = (u32x4*)(WT + (size_t)n * KD + k0);
#pragma unroll
  for (int j = 0; j < 4; ++j) {
    u32x4 o;
    o.x = buf[4 * j + 0];
    o.y = buf[4 * j + 1];
    o.z = buf[4 * j + 2];
    o.w = buf[4 * j + 3];
    dst[j] = o;
  }
}

// ---- 256x256 i8 GEMM ------------------------------------------------------

#define GLL16(g, l)                                                  \
  __builtin_amdgcn_global_load_lds(                                  \
      (const __attribute__((address_space(1))) void*)(g),            \
      (__attribute__((address_space(3))) void*)(l), 16, 0, 0)

#define BARRIER()    __builtin_amdgcn_s_barrier()
#define WAITL(N)     asm volatile("s_waitcnt lgkmcnt(" #N ")")
#define WAITV(N)     asm volatile("s_waitcnt vmcnt(" #N ")")
#define SCHED()      __builtin_amdgcn_sched_barrier(0)
#define PRIO1()      __builtin_amdgcn_s_setprio(1)
#define PRIO0()      __builtin_amdgcn_s_setprio(0)

// one operand tile = 256 rows x 64 int8 (16 KB) = 2 GLL16 per thread.
// LDS dest linear; 16B-granule swizzle: LDS slot s of row r holds source
// granule s ^ ((r>>1)&3) — same involution applied on read (rule #21).
__device__ __forceinline__ void stage_op(const signed char* g0, char* lbase,
                                         int w) {
  GLL16(g0, lbase + w * 1024);                              // rows 0-127
  GLL16(g0 + (size_t)128 * KD, lbase + 8192 + w * 1024);    // rows 128-255
}

__global__ __launch_bounds__(512, 2) void gemm_kernel(
    const signed char* __restrict__ Aq8,  // int8 [M][K]
    const signed char* __restrict__ Bq8,  // int8 [N][K] (W^T)
    const float* __restrict__ xs,         // [M] row scales
    const float* __restrict__ scale,      // [N]
    float* __restrict__ C) {              // f32 [M][N]
  __shared__ __align__(16) char Asm[2][16384];
  __shared__ __align__(16) char Bsm[2][16384];

  const int tid  = threadIdx.x;
  const int lane = tid & 63;
  const int w    = tid >> 6;   // wave 0..7
  const int wm   = w >> 2;     // 0..1 : A rows wm*128..+127
  const int wn   = w & 3;      // 0..3 : B cols wn*64..+63

  // 2D XCD supertiling (round 6)
  const int bid = blockIdx.x;            // 2048 = 8 XCD chunks x 256
  const int xcd = bid & 7;
  const int pos = bid >> 3;
  const int tm  = (xcd << 2) | (pos & 3);   // 0..31
  const int tn  = pos >> 2;                 // 0..63
  const size_t brow = (size_t)tm * 256;
  const size_t bcol = (size_t)tn * 256;

  // staging source addressing (pre-swizzled granule)
  const int srow  = w * 16 + (lane >> 2);                  // 0..127
  const int sgran = (lane & 3) ^ ((lane >> 3) & 3);
  const signed char* Ag = Aq8 + (brow + srow) * (size_t)KD + sgran * 16;
  const signed char* Bg = Bq8 + (bcol + srow) * (size_t)KD + sgran * 16;

  // fragment-read addressing: row = tile16 + r15, k-granule = lane>>4,
  // swizzled slot = kc ^ ((r15>>1)&3)  (row>>1&3 == r15>>1&3 since tile
  // bases are multiples of 16)
  const int r15  = lane & 15;
  const int kcsw = (((lane >> 4) ^ ((r15 >> 1) & 3)) << 4);

  i32x4 acc[8][4];
#pragma unroll
  for (int i = 0; i < 8; ++i)
#pragma unroll
    for (int j = 0; j < 4; ++j) acc[i][j] = (i32x4){0, 0, 0, 0};

  // ---- prologue: tiles 0 and 1 staged (8 GLL); tile1's 4 stay in flight ----
  stage_op(Ag,      &Asm[0][0], w);
  stage_op(Bg,      &Bsm[0][0], w);
  stage_op(Ag + 64, &Asm[1][0], w);
  stage_op(Bg + 64, &Bsm[1][0], w);
  SCHED();
  WAITV(4);   // tile0 resident; tile1's 4 loads in flight
  SCHED();
  BARRIER();
  SCHED();

  i32x4 a[8], b[4];
  // prime: aL of tile0 (4 reads, in flight into the first iteration)
  {
    const char* A0 = &Asm[0][0] + wm * 8192;
#pragma unroll
    for (int mi = 0; mi < 4; ++mi)
      a[mi] = *(const i32x4*)(A0 + (mi * 16 + r15) * 64 + kcsw);
  }
  SCHED();

  // ---- main loop: 64 K-tiles (1 MFMA K-step each) ----
#pragma unroll 2
  for (int it = 0; it < NT; ++it) {
    const int h = it & 1;
    const char* Ard  = &Asm[h][0] + wm * 8192;
    const char* ArdN = &Asm[h ^ 1][0] + wm * 8192;
    const char* Brd  = &Bsm[h][0] + wn * 4096;
    const size_t kb2 = (size_t)((it + 2) & (NT - 1)) * 64;

    // issue B (4 reads) then A-high (4 reads); aL(4) already in flight
#pragma unroll
    for (int ni = 0; ni < 4; ++ni)
      b[ni] = *(const i32x4*)(Brd + (ni * 16 + r15) * 64 + kcsw);
    SCHED();
#pragma unroll
    for (int mi = 0; mi < 4; ++mi)
      a[4 + mi] = *(const i32x4*)(Ard + ((4 + mi) * 16 + r15) * 64 + kcsw);
    SCHED();
    WAITL(4);   // aL + b resident; aH(4) in flight
    SCHED();
    PRIO1();
#pragma unroll
    for (int mi = 0; mi < 4; ++mi)       // 16 MFMA cover aH drain
#pragma unroll
      for (int ni = 0; ni < 4; ++ni)
        acc[mi][ni] = __builtin_amdgcn_mfma_i32_16x16x64_i8(
            a[mi], b[ni], acc[mi][ni], 0, 0, 0);
    PRIO0();
    SCHED();
    WAITL(0);   // aH resident; all my reads of buf h complete
    SCHED();
    PRIO1();
#pragma unroll
    for (int mi = 4; mi < 8; ++mi)       // 8 MFMA
#pragma unroll
      for (int ni = 0; ni < 2; ++ni)
        acc[mi][ni] = __builtin_amdgcn_mfma_i32_16x16x64_i8(
            a[mi], b[ni], acc[mi][ni], 0, 0, 0);
    PRIO0();
    SCHED();
    WAITV(0);   // tile it+1 resident in buf[h^1] (4 GLL issued last tile;
                // nothing newer in flight -> no depth lost)
    SCHED();
    BARRIER();  // RAW: buf[h^1] staging certified block-wide
    SCHED();
#pragma unroll
    for (int mi = 0; mi < 4; ++mi)       // prefetch aL of tile it+1
      a[mi] = *(const i32x4*)(ArdN + (mi * 16 + r15) * 64 + kcsw);
    SCHED();
    BARRIER();  // WAR: all waves' reads of buf[h] complete
    SCHED();
    stage_op(Ag + kb2, &Asm[h][0], w);   // tile it+2 (4 GLL)
    stage_op(Bg + kb2, &Bsm[h][0], w);
    SCHED();
    PRIO1();
#pragma unroll
    for (int mi = 4; mi < 8; ++mi)       // 8 MFMA cover aL' drain + stage
#pragma unroll
      for (int ni = 2; ni < 4; ++ni)
        acc[mi][ni] = __builtin_amdgcn_mfma_i32_16x16x64_i8(
            a[mi], b[ni], acc[mi][ni], 0, 0, 0);
    PRIO0();
    SCHED();
  }

  // ---- epilogue: float(acc) * xs[row] * (1/scale[col]) -> C ----
  const int r4 = (lane >> 4) << 2;
  float sxv[8][4];
#pragma unroll
  for (int mi = 0; mi < 8; ++mi)
#pragma unroll
    for (int r = 0; r < 4; ++r)
      sxv[mi][r] = xs[brow + wm * 128 + mi * 16 + r4 + r];
#pragma unroll
  for (int ni = 0; ni < 4; ++ni) {
    const size_t col = bcol + wn * 64 + ni * 16 + r15;
    const float inv = 1.0f / scale[col];
#pragma unroll
    for (int mi = 0; mi < 8; ++mi) {
      float* cp = C + (brow + wm * 128 + mi * 16 + r4) * (size_t)ND + col;
#pragma unroll
      for (int r = 0; r < 4; ++r)
        cp[(size_t)r * ND] = (float)acc[mi][ni][r] * sxv[mi][r] * inv;
    }
  }
}

}  // namespace

extern "C" void kernel_launch(void* const* d_in, const int* in_sizes, int n_in,
                              void* d_out, int out_size, void* d_ws,
                              size_t ws_size, hipStream_t stream) {
  const float* x     = (const float*)d_in[0];
  const int*   W     = (const int*)d_in[1];
  const float* scale = (const float*)d_in[2];
  float*       out   = (float*)d_out;

  signed char* xq = (signed char*)d_ws;                                  // 32 MB
  signed char* wq = (signed char*)d_ws + (size_t)32 * 1024 * 1024;       // 64 MB
  float*       xs = (float*)((char*)d_ws + (size_t)96 * 1024 * 1024);    // 32 KB

  quant_x_kernel<<<8192, 256, 0, stream>>>(x, xq, xs);
  transpose_w_kernel<<<4096, 256, 0, stream>>>(W, wq);
  gemm_kernel<<<2048, 512, 0, stream>>>(xq, wq, xs, scale, out);
}

// Round 10
// 745.678 us; speedup vs baseline: 2.0863x; 1.1271x over previous
//
#include <hip/hip_runtime.h>

// ---------------------------------------------------------------------------
// out[b,t,f] = sum_d x[b,t,d] * (W[d,f] / scale[f])
// GEMM: M=8192 (B*T), K=4096 (D), N=16384 (F)
// Round 10: occupancy fix. R9's wave used ~228 unified VGPR (100 + 128 acc)
// -> 2 waves/SIMD -> ONE block/CU (Occupancy 23.6% in every round). Shrink
// wave-tile to 64x64 (acc 64), block 256x128, LDS 48KB -> 2 blocks/CU,
// 4 waves/SIMD (__launch_bounds__(512,4)). i8 MFMA, 1 barrier/tile (merged
// RAW+WAR), cross-tile a-prefetch, granule swizzle, XCD supertile.
// ws: [0,32M) xq int8 ; [32M,96M) WT int8 ; [96M,+32K) xs f32.
// ---------------------------------------------------------------------------

namespace {

constexpr int MD = 8192;    // B*T
constexpr int ND = 16384;   // F
constexpr int KD = 4096;    // D
constexpr int NT = KD / 64; // 64 k-tiles of BK=64

typedef float fl4 __attribute__((ext_vector_type(4)));
typedef unsigned int u32x4 __attribute__((ext_vector_type(4)));
typedef int i32x4 __attribute__((ext_vector_type(4)));

__device__ __forceinline__ unsigned int pack4(fl4 v, float sc) {
  int q0 = __float2int_rn(v.x * sc);
  int q1 = __float2int_rn(v.y * sc);
  int q2 = __float2int_rn(v.z * sc);
  int q3 = __float2int_rn(v.w * sc);
  return (q0 & 0xFF) | ((q1 & 0xFF) << 8) | ((q2 & 0xFF) << 16) |
         ((q3 & 0xFF) << 24);
}

// ---- x fp32 [M][K] -> int8 [M][K] + per-row scale -------------------------
__global__ __launch_bounds__(256) void quant_x_kernel(
    const float* __restrict__ x, signed char* __restrict__ xq,
    float* __restrict__ xs) {
  const int row = blockIdx.x;
  const int t   = threadIdx.x;
  const float* xr = x + (size_t)row * KD + t * 16;
  fl4 v0 = *(const fl4*)(xr);
  fl4 v1 = *(const fl4*)(xr + 4);
  fl4 v2 = *(const fl4*)(xr + 8);
  fl4 v3 = *(const fl4*)(xr + 12);
  float m = 0.f;
  m = fmaxf(m, fmaxf(fmaxf(fabsf(v0.x), fabsf(v0.y)), fmaxf(fabsf(v0.z), fabsf(v0.w))));
  m = fmaxf(m, fmaxf(fmaxf(fabsf(v1.x), fabsf(v1.y)), fmaxf(fabsf(v1.z), fabsf(v1.w))));
  m = fmaxf(m, fmaxf(fmaxf(fabsf(v2.x), fabsf(v2.y)), fmaxf(fabsf(v2.z), fabsf(v2.w))));
  m = fmaxf(m, fmaxf(fmaxf(fabsf(v3.x), fabsf(v3.y)), fmaxf(fabsf(v3.z), fabsf(v3.w))));
#pragma unroll
  for (int off = 32; off; off >>= 1) m = fmaxf(m, __shfl_xor(m, off));
  __shared__ float red[4];
  if ((t & 63) == 0) red[t >> 6] = m;
  __syncthreads();
  m = fmaxf(fmaxf(red[0], red[1]), fmaxf(red[2], red[3]));
  const float sc = (m > 0.f) ? 127.0f / m : 0.f;
  if (t == 0) xs[row] = (m > 0.f) ? m / 127.0f : 0.f;
  u32x4 o;
  o.x = pack4(v0, sc);
  o.y = pack4(v1, sc);
  o.z = pack4(v2, sc);
  o.w = pack4(v3, sc);
  *(u32x4*)(xq + (size_t)row * KD + t * 16) = o;
}

// ---- W int32 [K][N] -> int8 W^T [N][K] ------------------------------------
__global__ __launch_bounds__(256) void transpose_w_kernel(
    const int* __restrict__ W, signed char* __restrict__ WT) {
  constexpr int KC = 64;
  const int nb = blockIdx.x & 63;
  const int kb = blockIdx.x >> 6;
  const int n  = nb * 256 + threadIdx.x;
  const int k0 = kb * KC;
  const int* src = W + (size_t)k0 * ND + n;
  unsigned int buf[16];
#pragma unroll
  for (int i = 0; i < KC; i += 4) {
    unsigned int b0 = (unsigned)src[(size_t)(i + 0) * ND] & 0xFF;
    unsigned int b1 = (unsigned)src[(size_t)(i + 1) * ND] & 0xFF;
    unsigned int b2 = (unsigned)src[(size_t)(i + 2) * ND] & 0xFF;
    unsigned int b3 = (unsigned)src[(size_t)(i + 3) * ND] & 0xFF;
    buf[i >> 2] = b0 | (b1 << 8) | (b2 << 16) | (b3 << 24);
  }
  u32x4* dst = (u32x4*)(WT + (size_t)n * KD + k0);
#pragma unroll
  for (int j = 0; j < 4; ++j) {
    u32x4 o;
    o.x = buf[4 * j + 0];
    o.y = buf[4 * j + 1];
    o.z = buf[4 * j + 2];
    o.w = buf[4 * j + 3];
    dst[j] = o;
  }
}

// ---- 256x128 i8 GEMM, 2 blocks/CU -----------------------------------------

#define GLL16(g, l)                                                  \
  __builtin_amdgcn_global_load_lds(                                  \
      (const __attribute__((address_space(1))) void*)(g),            \
      (__attribute__((address_space(3))) void*)(l), 16, 0, 0)

#define BARRIER()    __builtin_amdgcn_s_barrier()
#define WAITL(N)     asm volatile("s_waitcnt lgkmcnt(" #N ")")
#define WAITV(N)     asm volatile("s_waitcnt vmcnt(" #N ")")
#define SCHED()      __builtin_amdgcn_sched_barrier(0)
#define PRIO1()      __builtin_amdgcn_s_setprio(1)
#define PRIO0()      __builtin_amdgcn_s_setprio(0)

__global__ __launch_bounds__(512, 4) void gemm_kernel(
    const signed char* __restrict__ Aq8,  // int8 [M][K]
    const signed char* __restrict__ Bq8,  // int8 [N][K] (W^T)
    const float* __restrict__ xs,         // [M] row scales
    const float* __restrict__ scale,      // [N]
    float* __restrict__ C) {              // f32 [M][N]
  // A tile 256x64 (16KB), B tile 128x64 (8KB), double-buffered: 48KB.
  __shared__ __align__(16) char Asm[2][16384];
  __shared__ __align__(16) char Bsm[2][8192];

  const int tid  = threadIdx.x;
  const int lane = tid & 63;
  const int w    = tid >> 6;   // wave 0..7
  const int wm   = w >> 1;     // 0..3 : A rows wm*64..+63
  const int wn   = w & 1;      // 0..1 : B cols wn*64..+63

  // XCD supertile: xcd owns tm in [4c,4c+4), sweeps tn 0..127 tm-fastest.
  const int bid = blockIdx.x;            // 4096 = 8 chunks x 512
  const int xcd = bid & 7;
  const int pos = bid >> 3;              // 0..511
  const int tm  = (xcd << 2) | (pos & 3);   // 0..31
  const int tn  = pos >> 2;                 // 0..127
  const size_t brow = (size_t)tm * 256;
  const size_t bcol = (size_t)tn * 128;

  // staging: thread covers row tid>>2 (0..127), granule pre-swizzled
  const int srow  = tid >> 2;
  const int sgran = (tid & 3) ^ ((tid >> 3) & 3);
  const signed char* Ag = Aq8 + (brow + srow) * (size_t)KD + sgran * 16;
  const signed char* Bg = Bq8 + (bcol + srow) * (size_t)KD + sgran * 16;

  // fragment reads: row = base + r15, swizzled k-granule
  const int r15  = lane & 15;
  const int kcsw = (((lane >> 4) ^ ((r15 >> 1) & 3)) << 4);

  i32x4 acc[4][4];
#pragma unroll
  for (int i = 0; i < 4; ++i)
#pragma unroll
    for (int j = 0; j < 4; ++j) acc[i][j] = (i32x4){0, 0, 0, 0};

  // ---- prologue: tiles 0 (buf0) and 1 (buf1), 3 GLL each ----
  {
    GLL16(Ag,                        &Asm[0][0] + w * 1024);
    GLL16(Ag + (size_t)128 * KD,     &Asm[0][8192] + w * 1024);
    GLL16(Bg,                        &Bsm[0][0] + w * 1024);
    GLL16(Ag + 64,                   &Asm[1][0] + w * 1024);
    GLL16(Ag + (size_t)128 * KD + 64, &Asm[1][8192] + w * 1024);
    GLL16(Bg + 64,                   &Bsm[1][0] + w * 1024);
  }
  SCHED();
  WAITV(3);   // tile0 resident; tile1's 3 loads in flight
  SCHED();
  BARRIER();
  SCHED();

  i32x4 a[4], b[4];
  // prime a for tile 0
  {
    const char* Ab = &Asm[0][0] + (wm * 64 + r15) * 64 + kcsw;
#pragma unroll
    for (int mi = 0; mi < 4; ++mi) a[mi] = *(const i32x4*)(Ab + mi * 1024);
  }
  SCHED();

  // ---- main loop: 64 K-tiles, 1 barrier each ----
#pragma unroll 2
  for (int it = 0; it < NT; ++it) {
    const int h = it & 1;
    const char* Bb  = &Bsm[h][0] + (wn * 64 + r15) * 64 + kcsw;
    const char* AbN = &Asm[h ^ 1][0] + (wm * 64 + r15) * 64 + kcsw;
    const size_t kb2 = (size_t)((it + 2) & (NT - 1)) * 64;

    // issue b (4 reads); a (4) already in flight from last tile's prefetch
#pragma unroll
    for (int ni = 0; ni < 4; ++ni) b[ni] = *(const i32x4*)(Bb + ni * 1024);
    SCHED();
    WAITL(2);   // a + b0,b1 resident; b2,b3 in flight
    SCHED();
    PRIO1();
#pragma unroll
    for (int mi = 0; mi < 4; ++mi)   // 8 MFMA cover b2,b3 drain
#pragma unroll
      for (int ni = 0; ni < 2; ++ni)
        acc[mi][ni] = __builtin_amdgcn_mfma_i32_16x16x64_i8(
            a[mi], b[ni], acc[mi][ni], 0, 0, 0);
    PRIO0();
    SCHED();
    WAITL(0);   // all my reads of buf h complete
    SCHED();
    PRIO1();
#pragma unroll
    for (int mi = 0; mi < 2; ++mi)   // 4 MFMA
#pragma unroll
      for (int ni = 2; ni < 4; ++ni)
        acc[mi][ni] = __builtin_amdgcn_mfma_i32_16x16x64_i8(
            a[mi], b[ni], acc[mi][ni], 0, 0, 0);
    PRIO0();
    SCHED();
    WAITV(0);   // tile it+1 staging (3 GLL, issued last iter) resident
    SCHED();
    // single barrier: every wave has done lgkm(0) (buf[h] fully read) and
    // vmcnt(0) (buf[h^1] fully written) -> RAW + WAR certified at once.
    BARRIER();
    SCHED();
    // stage tile it+2 into buf[h]
    GLL16(Ag + kb2,                        &Asm[h][0] + w * 1024);
    GLL16(Ag + (size_t)128 * KD + kb2,     &Asm[h][8192] + w * 1024);
    GLL16(Bg + kb2,                        &Bsm[h][0] + w * 1024);
    SCHED();
    PRIO1();
#pragma unroll
    for (int mi = 2; mi < 4; ++mi)   // tail 4 MFMA cover GLL issue
#pragma unroll
      for (int ni = 2; ni < 4; ++ni)
        acc[mi][ni] = __builtin_amdgcn_mfma_i32_16x16x64_i8(
            a[mi], b[ni], acc[mi][ni], 0, 0, 0);
    PRIO0();
    SCHED();
    // prefetch a of tile it+1 from buf[h^1] (a regs dead)
#pragma unroll
    for (int mi = 0; mi < 4; ++mi) a[mi] = *(const i32x4*)(AbN + mi * 1024);
    SCHED();
  }

  // ---- epilogue: float(acc) * xs[row] * (1/scale[col]) -> C ----
  const int r4 = (lane >> 4) << 2;
  float sxv[4][4];
#pragma unroll
  for (int mi = 0; mi < 4; ++mi)
#pragma unroll
    for (int r = 0; r < 4; ++r)
      sxv[mi][r] = xs[brow + wm * 64 + mi * 16 + r4 + r];
#pragma unroll
  for (int ni = 0; ni < 4; ++ni) {
    const size_t col = bcol + wn * 64 + ni * 16 + r15;
    const float inv = 1.0f / scale[col];
#pragma unroll
    for (int mi = 0; mi < 4; ++mi) {
      float* cp = C + (brow + wm * 64 + mi * 16 + r4) * (size_t)ND + col;
#pragma unroll
      for (int r = 0; r < 4; ++r)
        cp[(size_t)r * ND] = (float)acc[mi][ni][r] * sxv[mi][r] * inv;
    }
  }
}

}  // namespace

extern "C" void kernel_launch(void* const* d_in, const int* in_sizes, int n_in,
                              void* d_out, int out_size, void* d_ws,
                              size_t ws_size, hipStream_t stream) {
  const float* x     = (const float*)d_in[0];
  const int*   W     = (const int*)d_in[1];
  const float* scale = (const float*)d_in[2];
  float*       out   = (float*)d_out;

  signed char* xq = (signed char*)d_ws;                                  // 32 MB
  signed char* wq = (signed char*)d_ws + (size_t)32 * 1024 * 1024;       // 64 MB
  float*       xs = (float*)((char*)d_ws + (size_t)96 * 1024 * 1024);    // 32 KB

  quant_x_kernel<<<8192, 256, 0, stream>>>(x, xq, xs);
  transpose_w_kernel<<<4096, 256, 0, stream>>>(W, wq);
  gemm_kernel<<<4096, 512, 0, stream>>>(xq, wq, xs, scale, out);
}